// Round 2
// baseline (19261.526 us; speedup 1.0000x reference)
//
#include <hip/hip_runtime.h>
#include <hip/hip_bf16.h>
#include <math.h>

// ---------------- problem constants ----------------
constexpr int B_    = 32;
constexpr int HIST_ = 10, C_ = 11, H_ = 15, W_ = 20;
constexpr int D_    = 256, NH_ = 4, NL_ = 4, HD_ = 64;
constexpr int OUT_  = 256, ADIM_ = 20;
constexpr int L_    = HIST_*H_*W_ + 1;      // 3001
constexpr int VIS_  = HIST_*C_*H_*W_;       // 33000
constexpr int NTOK  = B_*L_;                // 96032
constexpr int OBSROW = VIS_ + ADIM_;        // 33020

// chunking (to keep workspace small): 4 batches per attention chunk
constexpr int NBC   = 4;                    // batches per attn chunk
constexpr int NCH   = B_/NBC;               // 8 chunks
constexpr int RC    = NBC*L_;               // 12004 rows per chunk
constexpr int CAP   = RC*D_;                // 3,073,024 floats per chunk buffer

// ---------------- small utility kernels ----------------

__global__ void zero_kernel(float* __restrict__ p, int n) {
    int i = blockIdx.x*256 + threadIdx.x;
    if (i < n) p[i] = 0.f;
}

// Build x[b, l, d]: l==0 -> cls token; else project 11 channels.
__global__ void proj_kernel(const float* __restrict__ obs, const float* __restrict__ pw,
                            const float* __restrict__ pb, const float* __restrict__ cls,
                            float* __restrict__ x) {
    __shared__ float vis[C_];
    int n = blockIdx.x;            // 0..NTOK-1
    int b = n / L_, l = n % L_;
    int d = threadIdx.x;           // 0..255
    float out;
    if (l == 0) {
        out = cls[d];
    } else {
        int t = l - 1;
        int hist = t / (H_*W_);
        int rem  = t % (H_*W_);    // h*W + w
        if (d < C_) vis[d] = obs[(size_t)b*OBSROW + hist*(C_*H_*W_) + d*(H_*W_) + rem];
        __syncthreads();
        float acc = pb[d];
        #pragma unroll
        for (int c = 0; c < C_; ++c) acc += vis[c] * pw[c*D_ + d];
        out = acc;
    }
    x[(size_t)n*D_ + d] = out;
}

// LayerNorm over D=256. One wave per token, 4 tokens per block. Works in-place.
__global__ void ln_kernel(const float* __restrict__ in, const float* __restrict__ g,
                          const float* __restrict__ bt, float* __restrict__ out, int ntok) {
    int wave = threadIdx.x >> 6;
    int lane = threadIdx.x & 63;
    int n = blockIdx.x*4 + wave;
    if (n >= ntok) return;
    float4 v = ((const float4*)(in + (size_t)n*D_))[lane];
    float s  = v.x + v.y + v.z + v.w;
    float sq = v.x*v.x + v.y*v.y + v.z*v.z + v.w*v.w;
    #pragma unroll
    for (int off = 32; off; off >>= 1) { s += __shfl_xor(s, off); sq += __shfl_xor(sq, off); }
    float mean = s * (1.f/D_);
    float var  = sq * (1.f/D_) - mean*mean;
    float r = rsqrtf(var + 1e-5f);
    float4 gg = ((const float4*)g)[lane];
    float4 bb = ((const float4*)bt)[lane];
    float4 o;
    o.x = (v.x-mean)*r*gg.x + bb.x;
    o.y = (v.y-mean)*r*gg.y + bb.y;
    o.z = (v.z-mean)*r*gg.z + bb.z;
    o.w = (v.w-mean)*r*gg.w + bb.w;
    ((float4*)(out + (size_t)n*D_))[lane] = o;
}

// RoPE cos/sin table: tab[(l*32+i)*2] = cos(l * 10000^(-2i/64)), [..+1] = sin.
__global__ void rope_table_kernel(float* __restrict__ tab) {
    int idx = blockIdx.x*256 + threadIdx.x;
    if (idx >= L_*32) return;
    int t = idx >> 5, i = idx & 31;
    float freq = powf(10000.f, -2.f*(float)i/(float)HD_);
    float ang = (float)t * freq;
    tab[idx*2]   = cosf(ang);
    tab[idx*2+1] = sinf(ang);
}

// In-place rope + silu on a (ntok, D) chunk viewed as heads of 64.
// Chunk must start at a batch boundary (row n -> l = n % L_).
__global__ void rope_silu_kernel(float* __restrict__ q, const float* __restrict__ tab, int ntok) {
    int idx = blockIdx.x*256 + threadIdx.x;
    if (idx >= ntok*NH_*32) return;
    int i = idx & 31;
    int h = (idx >> 5) & (NH_-1);
    int n = idx >> 7;
    int l = n % L_;
    size_t base = (size_t)n*D_ + h*HD_;
    float x1 = q[base + i];
    float x2 = q[base + 32 + i];
    float c = tab[(l*32+i)*2], s = tab[(l*32+i)*2+1];
    float o1 = x1*c - x2*s;
    float o2 = x2*c + x1*s;
    o1 = o1 / (1.f + expf(-o1));
    o2 = o2 / (1.f + expf(-o2));
    q[base + i]      = o1;
    q[base + 32 + i] = o2;
}

// ---------------- tiled fp32 GEMM ----------------
// C[M,N] (+)= op(A[M,K] @ W[K,N] (+bias)). 64x64 tile, BK=16, 256 thr, 4x4/thread.
template<bool GELU, bool RES, bool BIAS>
__global__ void gemm_kernel(const float* __restrict__ A, const float* __restrict__ W,
                            const float* __restrict__ bias, float* __restrict__ C,
                            int M, int N, int K) {
    __shared__ float As[16][64];
    __shared__ float Bs[16][64];
    int tid = threadIdx.x;
    int row0 = blockIdx.y*64, col0 = blockIdx.x*64;
    int ty = tid >> 4, tx = tid & 15;
    int arow = tid >> 2, acseg = tid & 3;
    int brow = tid >> 4, bcol = (tid & 15)*4;
    float acc[4][4] = {};
    for (int k0 = 0; k0 < K; k0 += 16) {
        float4 a4 = make_float4(0.f,0.f,0.f,0.f);
        if (row0 + arow < M)
            a4 = *(const float4*)(A + (size_t)(row0+arow)*K + k0 + acseg*4);
        As[acseg*4+0][arow] = a4.x;
        As[acseg*4+1][arow] = a4.y;
        As[acseg*4+2][arow] = a4.z;
        As[acseg*4+3][arow] = a4.w;
        float4 b4 = *(const float4*)(W + (size_t)(k0+brow)*N + col0 + bcol);
        *(float4*)&Bs[brow][bcol] = b4;
        __syncthreads();
        #pragma unroll
        for (int k = 0; k < 16; ++k) {
            float4 av = *(const float4*)&As[k][ty*4];
            float4 bv = *(const float4*)&Bs[k][tx*4];
            acc[0][0] += av.x*bv.x; acc[0][1] += av.x*bv.y; acc[0][2] += av.x*bv.z; acc[0][3] += av.x*bv.w;
            acc[1][0] += av.y*bv.x; acc[1][1] += av.y*bv.y; acc[1][2] += av.y*bv.z; acc[1][3] += av.y*bv.w;
            acc[2][0] += av.z*bv.x; acc[2][1] += av.z*bv.y; acc[2][2] += av.z*bv.z; acc[2][3] += av.z*bv.w;
            acc[3][0] += av.w*bv.x; acc[3][1] += av.w*bv.y; acc[3][2] += av.w*bv.z; acc[3][3] += av.w*bv.w;
        }
        __syncthreads();
    }
    #pragma unroll
    for (int i = 0; i < 4; ++i) {
        int row = row0 + ty*4 + i;
        if (row >= M) continue;
        float4 o;
        float* op = &o.x;
        #pragma unroll
        for (int j = 0; j < 4; ++j) {
            float v = acc[i][j];
            if (BIAS) v += bias[col0 + tx*4 + j];
            if (GELU) v = 0.5f*v*(1.f + erff(v*0.70710678118654752f));
            op[j] = v;
        }
        float* cp = C + (size_t)row*N + col0 + tx*4;
        if (RES) {
            float4 old = *(const float4*)cp;
            o.x += old.x; o.y += old.y; o.z += old.z; o.w += old.w;
        }
        *(float4*)cp = o;
    }
}

// kv[bh,d,e] += sum over a chunk of l of k[b,l,h,d] * v[b,l,h,e]  (b chunk-local)
constexpr int KV_CH  = 512;
constexpr int KV_NCH = (L_ + KV_CH - 1) / KV_CH;  // 6
__global__ void kv_kernel(const float* __restrict__ Kt, const float* __restrict__ Vt,
                          float* __restrict__ kv) {
    __shared__ float ks[8][64], vs[8][64];
    int bid = blockIdx.x;
    int chunk = bid % KV_NCH;
    int bh = bid / KV_NCH;
    int b = bh / NH_, h = bh % NH_;
    int tid = threadIdx.x;
    int td = tid >> 4, te = tid & 15;
    float acc[4][4] = {};
    int l0 = chunk*KV_CH;
    int lend = min(l0 + KV_CH, L_);
    for (int lb = l0; lb < lend; lb += 8) {
        #pragma unroll
        for (int part = 0; part < 2; ++part) {
            int lin = part*256 + tid;          // 0..511
            int r = lin >> 6, c = lin & 63;
            bool ok = (lb + r < lend);
            size_t gi = ((size_t)b*L_ + lb + r)*D_ + h*HD_ + c;
            ks[r][c] = ok ? Kt[gi] : 0.f;
            vs[r][c] = ok ? Vt[gi] : 0.f;
        }
        __syncthreads();
        #pragma unroll
        for (int r = 0; r < 8; ++r) {
            float a0 = ks[r][td*4+0], a1 = ks[r][td*4+1], a2 = ks[r][td*4+2], a3 = ks[r][td*4+3];
            float4 bv = *(const float4*)&vs[r][te*4];
            acc[0][0] += a0*bv.x; acc[0][1] += a0*bv.y; acc[0][2] += a0*bv.z; acc[0][3] += a0*bv.w;
            acc[1][0] += a1*bv.x; acc[1][1] += a1*bv.y; acc[1][2] += a1*bv.z; acc[1][3] += a1*bv.w;
            acc[2][0] += a2*bv.x; acc[2][1] += a2*bv.y; acc[2][2] += a2*bv.z; acc[2][3] += a2*bv.w;
            acc[3][0] += a3*bv.x; acc[3][1] += a3*bv.y; acc[3][2] += a3*bv.z; acc[3][3] += a3*bv.w;
        }
        __syncthreads();
    }
    #pragma unroll
    for (int i = 0; i < 4; ++i)
        #pragma unroll
        for (int j = 0; j < 4; ++j)
            atomicAdd(kv + ((size_t)bh*64 + td*4+i)*64 + te*4+j, acc[i][j]);
}

// out[b,l,h,e] = (1/8) * sum_d q[b,l,h,d] * kv[bh,d,e]  (b chunk-local)
constexpr int ATT_NTL = (L_ + 63) / 64;  // 47
__global__ void attn_kernel(const float* __restrict__ Q, const float* __restrict__ kv,
                            float* __restrict__ Aout) {
    __shared__ float qT[64][65];   // [d][l] transposed, padded
    __shared__ float km[64][64];   // kv matrix [d][e]
    int bid = blockIdx.x;
    int tl = bid % ATT_NTL;
    int bh = bid / ATT_NTL;
    int b = bh / NH_, h = bh % NH_;
    int tid = threadIdx.x;
    int l0 = tl*64;
    #pragma unroll
    for (int p = 0; p < 16; ++p) {
        int lin = p*256 + tid;
        ((float*)km)[lin] = kv[(size_t)bh*4096 + lin];
        int r = lin >> 6, c = lin & 63;
        int l = l0 + r;
        qT[c][r] = (l < L_) ? Q[((size_t)b*L_ + l)*D_ + h*HD_ + c] : 0.f;
    }
    __syncthreads();
    int ty = tid >> 4, tx = tid & 15;
    float acc[4][4] = {};
    for (int k = 0; k < 64; ++k) {
        float a0 = qT[k][ty*4+0], a1 = qT[k][ty*4+1], a2 = qT[k][ty*4+2], a3 = qT[k][ty*4+3];
        float4 bv = *(const float4*)&km[k][tx*4];
        acc[0][0] += a0*bv.x; acc[0][1] += a0*bv.y; acc[0][2] += a0*bv.z; acc[0][3] += a0*bv.w;
        acc[1][0] += a1*bv.x; acc[1][1] += a1*bv.y; acc[1][2] += a1*bv.z; acc[1][3] += a1*bv.w;
        acc[2][0] += a2*bv.x; acc[2][1] += a2*bv.y; acc[2][2] += a2*bv.z; acc[2][3] += a2*bv.w;
        acc[3][0] += a3*bv.x; acc[3][1] += a3*bv.y; acc[3][2] += a3*bv.z; acc[3][3] += a3*bv.w;
    }
    #pragma unroll
    for (int i = 0; i < 4; ++i) {
        int l = l0 + ty*4 + i;
        if (l >= L_) continue;
        float4 o = make_float4(acc[i][0]*0.125f, acc[i][1]*0.125f, acc[i][2]*0.125f, acc[i][3]*0.125f);
        *(float4*)(Aout + ((size_t)b*L_ + l)*D_ + h*HD_ + tx*4) = o;
    }
}

// Final: LN(x[b,0,:]) with fng/fnb, concat action_feat, @ out_w + out_b.
__global__ void head_kernel(const float* __restrict__ x, const float* __restrict__ obs,
                            const float* __restrict__ fng, const float* __restrict__ fnb,
                            const float* __restrict__ ow, const float* __restrict__ ob,
                            float* __restrict__ out) {
    __shared__ float row[D_ + ADIM_];
    __shared__ float red[8];
    int b = blockIdx.x, tid = threadIdx.x;
    float v = x[((size_t)b*L_)*D_ + tid];
    float s = v, sq = v*v;
    #pragma unroll
    for (int off = 32; off; off >>= 1) { s += __shfl_xor(s, off); sq += __shfl_xor(sq, off); }
    int wave = tid >> 6, lane = tid & 63;
    if (lane == 0) { red[wave] = s; red[4+wave] = sq; }
    __syncthreads();
    s  = red[0]+red[1]+red[2]+red[3];
    sq = red[4]+red[5]+red[6]+red[7];
    float mean = s*(1.f/D_), var = sq*(1.f/D_) - mean*mean;
    float r = rsqrtf(var + 1e-5f);
    row[tid] = (v-mean)*r*fng[tid] + fnb[tid];
    if (tid < ADIM_) row[D_+tid] = obs[(size_t)b*OBSROW + VIS_ + tid];
    __syncthreads();
    float acc = ob[tid];
    for (int j = 0; j < D_+ADIM_; ++j) acc += row[j]*ow[j*OUT_ + tid];
    out[(size_t)b*OUT_ + tid] = acc;
}

// ---------------- launch ----------------
extern "C" void kernel_launch(void* const* d_in, const int* in_sizes, int n_in,
                              void* d_out, int out_size, void* d_ws, size_t ws_size,
                              hipStream_t stream) {
    const float* obs   = (const float*)d_in[0];
    const float* pw    = (const float*)d_in[1];
    const float* pb    = (const float*)d_in[2];
    const float* cls   = (const float*)d_in[3];
    const float* qw    = (const float*)d_in[4];
    const float* kw    = (const float*)d_in[5];
    const float* vw    = (const float*)d_in[6];
    const float* oww   = (const float*)d_in[7];
    const float* gq    = (const float*)d_in[8];
    const float* bq    = (const float*)d_in[9];
    const float* gk    = (const float*)d_in[10];
    const float* bk    = (const float*)d_in[11];
    const float* n1g   = (const float*)d_in[12];
    const float* n1b   = (const float*)d_in[13];
    const float* n2g   = (const float*)d_in[14];
    const float* n2b   = (const float*)d_in[15];
    const float* w1    = (const float*)d_in[16];
    const float* b1    = (const float*)d_in[17];
    const float* w2    = (const float*)d_in[18];
    const float* b2    = (const float*)d_in[19];
    const float* fng   = (const float*)d_in[20];
    const float* fnb   = (const float*)d_in[21];
    const float* outw  = (const float*)d_in[22];
    const float* outb  = (const float*)d_in[23];

    float* ws = (float*)d_ws;
    const size_t ND = (size_t)NTOK * D_;   // 24,584,192 floats (98.3 MB)
    float* x   = ws;                        // [ND]
    float* Ac  = x  + ND;                   // [CAP] chunk LN-out / attn-out
    float* Qc  = Ac + CAP;                  // [CAP] chunk Q / MLP hidden
    float* Kc  = Qc + CAP;                  // [CAP]
    float* Vc  = Kc + CAP;                  // [CAP]
    float* kvb = Vc + CAP;                  // NBC*NH*64*64 = 65,536
    float* tab = kvb + (size_t)NBC*NH_*HD_*HD_; // L*32*2 = 192,064
    // total = 37,133,888 floats = 148.5 MB  (fits modest ws_size)

    const int MTc = (RC + 63)/64;          // 188 row tiles per attn chunk
    const int lnc = (RC + 3)/4;            // 3001 LN blocks per attn chunk
    const int rs_blocks = (RC*NH_*32 + 255)/256;

    rope_table_kernel<<<(L_*32 + 255)/256, 256, 0, stream>>>(tab);
    proj_kernel<<<NTOK, 256, 0, stream>>>(obs, pw, pb, cls, x);

    for (int layer = 0; layer < NL_; ++layer) {
        const float* qw_l = qw + (size_t)layer*D_*D_;
        const float* kw_l = kw + (size_t)layer*D_*D_;
        const float* vw_l = vw + (size_t)layer*D_*D_;
        const float* ow_l = oww + (size_t)layer*D_*D_;
        const float* w1_l = w1 + (size_t)layer*D_*4*D_;
        const float* b1_l = b1 + (size_t)layer*4*D_;
        const float* w2_l = w2 + (size_t)layer*4*D_*D_;
        const float* b2_l = b2 + (size_t)layer*D_;

        // ---- attention, per chunk of NBC batches ----
        for (int c = 0; c < NCH; ++c) {
            float* xc = x + (size_t)c*CAP;
            ln_kernel<<<lnc, 256, 0, stream>>>(xc, n1g + layer*D_, n1b + layer*D_, Ac, RC);
            gemm_kernel<false,false,false><<<dim3(4, MTc), 256, 0, stream>>>(Ac, qw_l, nullptr, Qc, RC, D_, D_);
            gemm_kernel<false,false,false><<<dim3(4, MTc), 256, 0, stream>>>(Ac, kw_l, nullptr, Kc, RC, D_, D_);
            gemm_kernel<false,false,false><<<dim3(4, MTc), 256, 0, stream>>>(Ac, vw_l, nullptr, Vc, RC, D_, D_);
            ln_kernel<<<lnc, 256, 0, stream>>>(Qc, gq + layer*D_, bq + layer*D_, Qc, RC);
            ln_kernel<<<lnc, 256, 0, stream>>>(Kc, gk + layer*D_, bk + layer*D_, Kc, RC);
            rope_silu_kernel<<<rs_blocks, 256, 0, stream>>>(Qc, tab, RC);
            rope_silu_kernel<<<rs_blocks, 256, 0, stream>>>(Kc, tab, RC);
            zero_kernel<<<(NBC*NH_*HD_*HD_ + 255)/256, 256, 0, stream>>>(kvb, NBC*NH_*HD_*HD_);
            kv_kernel<<<NBC*NH_*KV_NCH, 256, 0, stream>>>(Kc, Vc, kvb);
            attn_kernel<<<NBC*NH_*ATT_NTL, 256, 0, stream>>>(Qc, kvb, Ac);
            gemm_kernel<false,true,false><<<dim3(4, MTc), 256, 0, stream>>>(Ac, ow_l, nullptr, xc, RC, D_, D_);
        }

        // ---- MLP, per batch (3001 rows); hidden reuses Qc (exact fit) ----
        const int MB = L_;                  // 3001 rows
        const int MBT = (MB + 63)/64;       // 47
        for (int m = 0; m < B_; ++m) {
            float* xm = x + (size_t)m*L_*D_;
            ln_kernel<<<(MB+3)/4, 256, 0, stream>>>(xm, n2g + layer*D_, n2b + layer*D_, Ac, MB);
            gemm_kernel<true,false,true><<<dim3(16, MBT), 256, 0, stream>>>(Ac, w1_l, b1_l, Qc, MB, 4*D_, D_);
            gemm_kernel<false,true,true><<<dim3(4, MBT), 256, 0, stream>>>(Qc, w2_l, b2_l, xm, MB, D_, 4*D_);
        }
    }

    head_kernel<<<B_, 256, 0, stream>>>(x, obs, fng, fnb, outw, outb, (float*)d_out);
}

// Round 3
// 6316.105 us; speedup vs baseline: 3.0496x; 3.0496x over previous
//
#include <hip/hip_runtime.h>
#include <math.h>

typedef unsigned short u16;
typedef __attribute__((ext_vector_type(8))) short short8;
typedef __attribute__((ext_vector_type(4))) short short4v;
typedef __attribute__((ext_vector_type(4))) float f32x4;

// ---------------- problem constants ----------------
constexpr int B_    = 32;
constexpr int HIST_ = 10, C_ = 11, H_ = 15, W_ = 20;
constexpr int D_    = 256, NH_ = 4, NL_ = 4, HD_ = 64;
constexpr int OUT_  = 256, ADIM_ = 20;
constexpr int L_    = HIST_*H_*W_ + 1;      // 3001
constexpr int VIS_  = HIST_*C_*H_*W_;       // 33000
constexpr int NTOK  = B_*L_;                // 96032
constexpr int OBSROW = VIS_ + ADIM_;        // 33020

// ---------------- bf16 helpers (bit-level, RNE) ----------------
__device__ __forceinline__ float bf2f(u16 u) {
    return __uint_as_float(((unsigned)u) << 16);
}
__device__ __forceinline__ u16 f2bf(float f) {
    unsigned u = __float_as_uint(f);
    u = u + 0x7FFFu + ((u >> 16) & 1u);
    return (u16)(u >> 16);
}

__device__ __forceinline__ f32x4 mfma16(short8 a, short8 b, f32x4 c) {
    return __builtin_amdgcn_mfma_f32_16x16x32_bf16(a, b, c, 0, 0, 0);
}

// ---------------- setup kernels ----------------

// dst[l][n][k] = bf16(src[l][k][n])  (weight transpose + convert)
__global__ void wcvt_kernel(const float* __restrict__ src, u16* __restrict__ dst,
                            int Nn, int Kk) {
    int idx = blockIdx.x*256 + threadIdx.x;
    int tot = NL_*Nn*Kk;
    if (idx >= tot) return;
    int l = idx / (Nn*Kk);
    int rem = idx % (Nn*Kk);
    int n = rem / Kk, k = rem % Kk;
    dst[idx] = f2bf(src[(size_t)l*Kk*Nn + (size_t)k*Nn + n]);
}

// RoPE cos/sin table: tab[(l*32+i)*2] = cos(l*10000^(-2i/64)), +1 = sin
__global__ void rope_table_kernel(float* __restrict__ tab) {
    int idx = blockIdx.x*256 + threadIdx.x;
    if (idx >= L_*32) return;
    int t = idx >> 5, i = idx & 31;
    float freq = powf(10000.f, -2.f*(float)i/(float)HD_);
    float ang = (float)t * freq;
    tab[idx*2]   = cosf(ang);
    tab[idx*2+1] = sinf(ang);
}

// Build x[b,l,d] fp32: l==0 -> cls; else project 11 channels
__global__ void proj_kernel(const float* __restrict__ obs, const float* __restrict__ pw,
                            const float* __restrict__ pb, const float* __restrict__ cls,
                            float* __restrict__ x) {
    __shared__ float vis[C_];
    int n = blockIdx.x;
    int b = n / L_, l = n % L_;
    int d = threadIdx.x;
    float out;
    if (l == 0) {
        out = cls[d];
    } else {
        int t = l - 1;
        int hist = t / (H_*W_);
        int rem  = t % (H_*W_);
        if (d < C_) vis[d] = obs[(size_t)b*OBSROW + hist*(C_*H_*W_) + d*(H_*W_) + rem];
        __syncthreads();
        float acc = pb[d];
        #pragma unroll
        for (int c = 0; c < C_; ++c) acc += vis[c] * pw[c*D_ + d];
        out = acc;
    }
    x[(size_t)n*D_ + d] = out;
}

// ---------------- LayerNorm fp32 -> bf16 ----------------
__global__ __launch_bounds__(256) void ln_f2b_kernel(const float* __restrict__ in,
        const float* __restrict__ g, const float* __restrict__ bt,
        u16* __restrict__ out, int ntok) {
    int wave = threadIdx.x >> 6, lane = threadIdx.x & 63;
    int n = blockIdx.x*4 + wave;
    if (n >= ntok) return;
    float4 v = ((const float4*)(in + (size_t)n*D_))[lane];
    float s  = v.x + v.y + v.z + v.w;
    float sq = v.x*v.x + v.y*v.y + v.z*v.z + v.w*v.w;
    #pragma unroll
    for (int off = 32; off; off >>= 1) { s += __shfl_xor(s, off); sq += __shfl_xor(sq, off); }
    float mean = s * (1.f/D_);
    float var  = sq * (1.f/D_) - mean*mean;
    float r = rsqrtf(var + 1e-5f);
    float4 gg = ((const float4*)g)[lane];
    float4 bb = ((const float4*)bt)[lane];
    short4v o;
    o.x = (short)f2bf((v.x-mean)*r*gg.x + bb.x);
    o.y = (short)f2bf((v.y-mean)*r*gg.y + bb.y);
    o.z = (short)f2bf((v.z-mean)*r*gg.z + bb.z);
    o.w = (short)f2bf((v.w-mean)*r*gg.w + bb.w);
    *(short4v*)(out + (size_t)n*D_ + lane*4) = o;
}

// ---------------- fused LN + RoPE + SiLU (bf16 in-place) ----------------
__global__ __launch_bounds__(256) void lnrope_kernel(u16* __restrict__ q,
        const float* __restrict__ g, const float* __restrict__ bt,
        const float* __restrict__ tab, int ntok) {
    int wave = threadIdx.x >> 6, lane = threadIdx.x & 63;
    int n = blockIdx.x*4 + wave;
    if (n >= ntok) return;
    int l = n % L_;
    short4v raw = *(const short4v*)(q + (size_t)n*D_ + lane*4);
    float v0 = bf2f((u16)raw.x), v1 = bf2f((u16)raw.y), v2 = bf2f((u16)raw.z), v3 = bf2f((u16)raw.w);
    float s  = v0+v1+v2+v3;
    float sq = v0*v0+v1*v1+v2*v2+v3*v3;
    #pragma unroll
    for (int off = 32; off; off >>= 1) { s += __shfl_xor(s, off); sq += __shfl_xor(sq, off); }
    float mean = s * (1.f/D_);
    float var  = sq * (1.f/D_) - mean*mean;
    float r = rsqrtf(var + 1e-5f);
    float4 gg = ((const float4*)g)[lane];
    float4 bb = ((const float4*)bt)[lane];
    float o0 = (v0-mean)*r*gg.x + bb.x;
    float o1 = (v1-mean)*r*gg.y + bb.y;
    float o2 = (v2-mean)*r*gg.z + bb.z;
    float o3 = (v3-mean)*r*gg.w + bb.w;
    // rope: partner is lane^8 (d +/- 32 within the 64-wide head)
    float p0 = __shfl_xor(o0, 8), p1 = __shfl_xor(o1, 8);
    float p2 = __shfl_xor(o2, 8), p3 = __shfl_xor(o3, 8);
    bool first = (lane & 15) < 8;
    const float4* tp = (const float4*)(tab + ((size_t)l*32 + (lane&7)*4)*2);
    float4 t01 = tp[0], t23 = tp[1];
    float r0 = first ? o0*t01.x - p0*t01.y : o0*t01.x + p0*t01.y;
    float r1 = first ? o1*t01.z - p1*t01.w : o1*t01.z + p1*t01.w;
    float r2 = first ? o2*t23.x - p2*t23.y : o2*t23.x + p2*t23.y;
    float r3 = first ? o3*t23.z - p3*t23.w : o3*t23.z + p3*t23.w;
    r0 = r0 / (1.f + expf(-r0));
    r1 = r1 / (1.f + expf(-r1));
    r2 = r2 / (1.f + expf(-r2));
    r3 = r3 / (1.f + expf(-r3));
    short4v o;
    o.x = (short)f2bf(r0); o.y = (short)f2bf(r1);
    o.z = (short)f2bf(r2); o.w = (short)f2bf(r3);
    *(short4v*)(q + (size_t)n*D_ + lane*4) = o;
}

// ---------------- bf16 MFMA GEMM ----------------
// C[M,N] = A[M,K] @ Wt[N,K]^T, 128x128 tile, BK=32, 4 waves (2x2), 16x16x32 MFMA.
// EPI: 0 = bf16 out; 1 = +bias, GELU, bf16 out; 2 = fp32 residual add; 3 = +bias, fp32 residual add
template<int EPI>
__global__ __launch_bounds__(256) void gemm_bf16(const u16* __restrict__ A,
        const u16* __restrict__ Wt, const float* __restrict__ bias,
        u16* __restrict__ Cb, float* __restrict__ Xres, int M, int N, int K) {
    __shared__ u16 As[128][32];
    __shared__ u16 Bs[128][32];
    const int tid = threadIdx.x;
    const int row0 = blockIdx.y*128, col0 = blockIdx.x*128;
    const int wid = tid >> 6, lane = tid & 63;
    const int wr = wid >> 1, wc = wid & 1;

    f32x4 acc[4][4];
    #pragma unroll
    for (int i = 0; i < 4; ++i)
        #pragma unroll
        for (int j = 0; j < 4; ++j) {
            f32x4 z; z.x = 0.f; z.y = 0.f; z.z = 0.f; z.w = 0.f;
            acc[i][j] = z;
        }

    // staging assignments: thread t -> row t>>1, k-half t&1 (16 bf16 = 2x short8)
    const int sr = tid >> 1, hf = tid & 1;
    const int sw = (sr >> 1) & 3;                 // swizzle bits (row bits 1..2)
    u16* ap0 = &As[sr][(((hf*2+0) ^ sw) & 3) * 8];
    u16* ap1 = &As[sr][(((hf*2+1) ^ sw) & 3) * 8];
    u16* bp0 = &Bs[sr][(((hf*2+0) ^ sw) & 3) * 8];
    u16* bp1 = &Bs[sr][(((hf*2+1) ^ sw) & 3) * 8];
    const bool arow_ok = (row0 + sr) < M;
    const u16* agp = A  + (size_t)(row0 + sr)*K + hf*16;
    const u16* bgp = Wt + (size_t)(col0 + sr)*K + hf*16;

    const int kg = lane >> 4, li = lane & 15;
    const int sidx = ((kg ^ ((li >> 1) & 3)) & 3) * 8;   // read-side swizzled slot

    for (int k0 = 0; k0 < K; k0 += 32) {
        short8 a0 = {0,0,0,0,0,0,0,0}, a1 = {0,0,0,0,0,0,0,0};
        if (arow_ok) {
            a0 = *(const short8*)(agp + k0);
            a1 = *(const short8*)(agp + k0 + 8);
        }
        short8 b0 = *(const short8*)(bgp + k0);
        short8 b1 = *(const short8*)(bgp + k0 + 8);
        __syncthreads();
        *(short8*)ap0 = a0; *(short8*)ap1 = a1;
        *(short8*)bp0 = b0; *(short8*)bp1 = b1;
        __syncthreads();

        short8 af[4], bfr[4];
        #pragma unroll
        for (int mi = 0; mi < 4; ++mi)
            af[mi] = *(const short8*)&As[wr*64 + mi*16 + li][sidx];
        #pragma unroll
        for (int ni = 0; ni < 4; ++ni)
            bfr[ni] = *(const short8*)&Bs[wc*64 + ni*16 + li][sidx];
        #pragma unroll
        for (int mi = 0; mi < 4; ++mi)
            #pragma unroll
            for (int ni = 0; ni < 4; ++ni)
                acc[mi][ni] = mfma16(af[mi], bfr[ni], acc[mi][ni]);
    }

    // epilogue: D row = (lane>>4)*4 + r, col = lane&15 within each 16x16 frag
    #pragma unroll
    for (int mi = 0; mi < 4; ++mi) {
        int rbase = row0 + wr*64 + mi*16 + kg*4;
        #pragma unroll
        for (int ni = 0; ni < 4; ++ni) {
            int col = col0 + wc*64 + ni*16 + li;
            #pragma unroll
            for (int r = 0; r < 4; ++r) {
                int row = rbase + r;
                if (row >= M) continue;
                float v = acc[mi][ni][r];
                if (EPI == 1) { v += bias[col]; v = 0.5f*v*(1.f + erff(v*0.70710678118654752f)); }
                if (EPI == 3) { v += bias[col]; }
                if (EPI == 0 || EPI == 1) Cb[(size_t)row*N + col] = f2bf(v);
                else                      Xres[(size_t)row*N + col] += v;
            }
        }
    }
}

// ---------------- kv = K^T V per (b,h), fp32 accum, bf16 out [d][e] ----------------
__global__ __launch_bounds__(256) void kv_kernel(const u16* __restrict__ Kt,
        const u16* __restrict__ Vt, u16* __restrict__ kvb) {
    __shared__ float ks[16][64], vs[16][64];
    int bh = blockIdx.x;
    int b = bh >> 2, h = bh & 3;
    int tid = threadIdx.x;
    int td = tid >> 4, te = tid & 15;
    int sr = tid >> 4, sc0 = (tid & 15)*4;
    float acc[4][4] = {};
    for (int lb = 0; lb < L_; lb += 16) {
        bool ok = (lb + sr) < L_;
        size_t gi = ((size_t)b*L_ + lb + sr)*D_ + h*HD_ + sc0;
        if (ok) {
            short4v kk = *(const short4v*)(Kt + gi);
            short4v vv = *(const short4v*)(Vt + gi);
            ks[sr][sc0+0] = bf2f((u16)kk.x); ks[sr][sc0+1] = bf2f((u16)kk.y);
            ks[sr][sc0+2] = bf2f((u16)kk.z); ks[sr][sc0+3] = bf2f((u16)kk.w);
            vs[sr][sc0+0] = bf2f((u16)vv.x); vs[sr][sc0+1] = bf2f((u16)vv.y);
            vs[sr][sc0+2] = bf2f((u16)vv.z); vs[sr][sc0+3] = bf2f((u16)vv.w);
        } else {
            ks[sr][sc0+0]=0.f; ks[sr][sc0+1]=0.f; ks[sr][sc0+2]=0.f; ks[sr][sc0+3]=0.f;
            vs[sr][sc0+0]=0.f; vs[sr][sc0+1]=0.f; vs[sr][sc0+2]=0.f; vs[sr][sc0+3]=0.f;
        }
        __syncthreads();
        #pragma unroll
        for (int r = 0; r < 16; ++r) {
            float a0 = ks[r][td*4+0], a1 = ks[r][td*4+1], a2 = ks[r][td*4+2], a3 = ks[r][td*4+3];
            float4 bv = *(const float4*)&vs[r][te*4];
            acc[0][0] += a0*bv.x; acc[0][1] += a0*bv.y; acc[0][2] += a0*bv.z; acc[0][3] += a0*bv.w;
            acc[1][0] += a1*bv.x; acc[1][1] += a1*bv.y; acc[1][2] += a1*bv.z; acc[1][3] += a1*bv.w;
            acc[2][0] += a2*bv.x; acc[2][1] += a2*bv.y; acc[2][2] += a2*bv.z; acc[2][3] += a2*bv.w;
            acc[3][0] += a3*bv.x; acc[3][1] += a3*bv.y; acc[3][2] += a3*bv.z; acc[3][3] += a3*bv.w;
        }
        __syncthreads();
    }
    #pragma unroll
    for (int i = 0; i < 4; ++i) {
        short4v o;
        o.x = (short)f2bf(acc[i][0]); o.y = (short)f2bf(acc[i][1]);
        o.z = (short)f2bf(acc[i][2]); o.w = (short)f2bf(acc[i][3]);
        *(short4v*)(kvb + (size_t)bh*4096 + (td*4+i)*64 + te*4) = o;
    }
}

// ---------------- attn: out = Q @ kv / 8, bf16 I/O, fp32 compute ----------------
constexpr int ATT_NTL = (L_ + 63) / 64;  // 47
__global__ __launch_bounds__(256) void attn_kernel(const u16* __restrict__ Q,
        const u16* __restrict__ kvb, u16* __restrict__ Aout) {
    __shared__ float qT[64][65];   // [d][l]
    __shared__ float km[64][64];   // [d][e]
    int tl = blockIdx.x;
    int bh = blockIdx.y;
    int b = bh >> 2, h = bh & 3;
    int tid = threadIdx.x;
    int l0 = tl*64;
    #pragma unroll
    for (int p = 0; p < 16; ++p) {
        int lin = p*256 + tid;
        ((float*)km)[lin] = bf2f(kvb[(size_t)bh*4096 + lin]);
    }
    #pragma unroll
    for (int p = 0; p < 4; ++p) {
        int u = p*256 + tid;           // 1024 short4 units
        int r = u >> 4, c0 = (u & 15)*4;
        int l = l0 + r;
        if (l < L_) {
            short4v qq = *(const short4v*)(Q + ((size_t)b*L_ + l)*D_ + h*HD_ + c0);
            qT[c0+0][r] = bf2f((u16)qq.x); qT[c0+1][r] = bf2f((u16)qq.y);
            qT[c0+2][r] = bf2f((u16)qq.z); qT[c0+3][r] = bf2f((u16)qq.w);
        } else {
            qT[c0+0][r]=0.f; qT[c0+1][r]=0.f; qT[c0+2][r]=0.f; qT[c0+3][r]=0.f;
        }
    }
    __syncthreads();
    int ty = tid >> 4, tx = tid & 15;
    float acc[4][4] = {};
    for (int k = 0; k < 64; ++k) {
        float a0 = qT[k][ty*4+0], a1 = qT[k][ty*4+1], a2 = qT[k][ty*4+2], a3 = qT[k][ty*4+3];
        float4 bv = *(const float4*)&km[k][tx*4];
        acc[0][0] += a0*bv.x; acc[0][1] += a0*bv.y; acc[0][2] += a0*bv.z; acc[0][3] += a0*bv.w;
        acc[1][0] += a1*bv.x; acc[1][1] += a1*bv.y; acc[1][2] += a1*bv.z; acc[1][3] += a1*bv.w;
        acc[2][0] += a2*bv.x; acc[2][1] += a2*bv.y; acc[2][2] += a2*bv.z; acc[2][3] += a2*bv.w;
        acc[3][0] += a3*bv.x; acc[3][1] += a3*bv.y; acc[3][2] += a3*bv.z; acc[3][3] += a3*bv.w;
    }
    #pragma unroll
    for (int i = 0; i < 4; ++i) {
        int l = l0 + ty*4 + i;
        if (l >= L_) continue;
        short4v o;
        o.x = (short)f2bf(acc[i][0]*0.125f); o.y = (short)f2bf(acc[i][1]*0.125f);
        o.z = (short)f2bf(acc[i][2]*0.125f); o.w = (short)f2bf(acc[i][3]*0.125f);
        *(short4v*)(Aout + ((size_t)b*L_ + l)*D_ + h*HD_ + tx*4) = o;
    }
}

// ---------------- head ----------------
__global__ void head_kernel(const float* __restrict__ x, const float* __restrict__ obs,
                            const float* __restrict__ fng, const float* __restrict__ fnb,
                            const float* __restrict__ ow, const float* __restrict__ ob,
                            float* __restrict__ out) {
    __shared__ float row[D_ + ADIM_];
    __shared__ float red[8];
    int b = blockIdx.x, tid = threadIdx.x;
    float v = x[((size_t)b*L_)*D_ + tid];
    float s = v, sq = v*v;
    #pragma unroll
    for (int off = 32; off; off >>= 1) { s += __shfl_xor(s, off); sq += __shfl_xor(sq, off); }
    int wave = tid >> 6, lane = tid & 63;
    if (lane == 0) { red[wave] = s; red[4+wave] = sq; }
    __syncthreads();
    s  = red[0]+red[1]+red[2]+red[3];
    sq = red[4]+red[5]+red[6]+red[7];
    float mean = s*(1.f/D_), var = sq*(1.f/D_) - mean*mean;
    float r = rsqrtf(var + 1e-5f);
    row[tid] = (v-mean)*r*fng[tid] + fnb[tid];
    if (tid < ADIM_) row[D_+tid] = obs[(size_t)b*OBSROW + VIS_ + tid];
    __syncthreads();
    float acc = ob[tid];
    for (int j = 0; j < D_+ADIM_; ++j) acc += row[j]*ow[j*OUT_ + tid];
    out[(size_t)b*OUT_ + tid] = acc;
}

// ---------------- launch ----------------
extern "C" void kernel_launch(void* const* d_in, const int* in_sizes, int n_in,
                              void* d_out, int out_size, void* d_ws, size_t ws_size,
                              hipStream_t stream) {
    const float* obs   = (const float*)d_in[0];
    const float* pw    = (const float*)d_in[1];
    const float* pb    = (const float*)d_in[2];
    const float* cls   = (const float*)d_in[3];
    const float* qw    = (const float*)d_in[4];
    const float* kw    = (const float*)d_in[5];
    const float* vw    = (const float*)d_in[6];
    const float* oww   = (const float*)d_in[7];
    const float* gq    = (const float*)d_in[8];
    const float* bq    = (const float*)d_in[9];
    const float* gk    = (const float*)d_in[10];
    const float* bk    = (const float*)d_in[11];
    const float* n1g   = (const float*)d_in[12];
    const float* n1b   = (const float*)d_in[13];
    const float* n2g   = (const float*)d_in[14];
    const float* n2b   = (const float*)d_in[15];
    const float* w1    = (const float*)d_in[16];
    const float* b1    = (const float*)d_in[17];
    const float* w2    = (const float*)d_in[18];
    const float* b2    = (const float*)d_in[19];
    const float* fng   = (const float*)d_in[20];
    const float* fnb   = (const float*)d_in[21];
    const float* outw  = (const float*)d_in[22];
    const float* outb  = (const float*)d_in[23];

    // ---- workspace layout ----
    float* x = (float*)d_ws;                               // NTOK*256 fp32
    u16* qwT = (u16*)(x + (size_t)NTOK*D_);
    u16* kwT = qwT + (size_t)NL_*65536;
    u16* vwT = kwT + (size_t)NL_*65536;
    u16* owT = vwT + (size_t)NL_*65536;
    u16* w1T = owT + (size_t)NL_*65536;                    // [NL][1024][256]
    u16* w2T = w1T + (size_t)NL_*262144;                   // [NL][256][1024]
    float* tab = (float*)(w2T + (size_t)NL_*262144);       // L*32*2 fp32
    u16* bufs = (u16*)(tab + (size_t)L_*32*2);

    size_t fixedB = (size_t)((char*)bufs - (char*)d_ws);
    auto needed = [&](int nb) -> size_t {
        size_t ch = (size_t)nb * L_ * D_;
        return fixedB + (ch*5 + (size_t)nb*L_*1024 + (size_t)nb*NH_*4096) * 2;
    };
    int nbc = 32;
    while (nbc > 1 && needed(nbc) > ws_size) nbc >>= 1;
    const int nch = B_ / nbc;
    const int RCn = nbc * L_;
    const size_t CH = (size_t)nbc * L_ * D_;

    u16* Xn  = bufs;
    u16* Qc  = Xn + CH;
    u16* Kc  = Qc + CH;
    u16* Vc  = Kc + CH;
    u16* Ac  = Vc + CH;
    u16* Hc  = Ac + CH;                                    // nbc*L*1024
    u16* kvb = Hc + (size_t)nbc*L_*1024;                   // nbc*4*4096

    // ---- setup ----
    wcvt_kernel<<<(NL_*65536 + 255)/256, 256, 0, stream>>>(qw,  qwT, 256, 256);
    wcvt_kernel<<<(NL_*65536 + 255)/256, 256, 0, stream>>>(kw,  kwT, 256, 256);
    wcvt_kernel<<<(NL_*65536 + 255)/256, 256, 0, stream>>>(vw,  vwT, 256, 256);
    wcvt_kernel<<<(NL_*65536 + 255)/256, 256, 0, stream>>>(oww, owT, 256, 256);
    wcvt_kernel<<<(NL_*262144 + 255)/256, 256, 0, stream>>>(w1, w1T, 1024, 256);
    wcvt_kernel<<<(NL_*262144 + 255)/256, 256, 0, stream>>>(w2, w2T, 256, 1024);
    rope_table_kernel<<<(L_*32 + 255)/256, 256, 0, stream>>>(tab);
    proj_kernel<<<NTOK, 256, 0, stream>>>(obs, pw, pb, cls, x);

    const int gy  = (RCn + 127)/128;
    const int lnb = (RCn + 3)/4;

    for (int layer = 0; layer < NL_; ++layer) {
        const u16* qwT_l = qwT + (size_t)layer*65536;
        const u16* kwT_l = kwT + (size_t)layer*65536;
        const u16* vwT_l = vwT + (size_t)layer*65536;
        const u16* owT_l = owT + (size_t)layer*65536;
        const u16* w1T_l = w1T + (size_t)layer*262144;
        const u16* w2T_l = w2T + (size_t)layer*262144;
        const float* b1_l = b1 + (size_t)layer*1024;
        const float* b2_l = b2 + (size_t)layer*D_;

        for (int c = 0; c < nch; ++c) {
            float* xc = x + (size_t)c*RCn*D_;
            ln_f2b_kernel<<<lnb, 256, 0, stream>>>(xc, n1g + layer*D_, n1b + layer*D_, Xn, RCn);
            gemm_bf16<0><<<dim3(2, gy), 256, 0, stream>>>(Xn, qwT_l, nullptr, Qc, nullptr, RCn, 256, 256);
            gemm_bf16<0><<<dim3(2, gy), 256, 0, stream>>>(Xn, kwT_l, nullptr, Kc, nullptr, RCn, 256, 256);
            gemm_bf16<0><<<dim3(2, gy), 256, 0, stream>>>(Xn, vwT_l, nullptr, Vc, nullptr, RCn, 256, 256);
            lnrope_kernel<<<lnb, 256, 0, stream>>>(Qc, gq + layer*D_, bq + layer*D_, tab, RCn);
            lnrope_kernel<<<lnb, 256, 0, stream>>>(Kc, gk + layer*D_, bk + layer*D_, tab, RCn);
            kv_kernel<<<nbc*NH_, 256, 0, stream>>>(Kc, Vc, kvb);
            attn_kernel<<<dim3(ATT_NTL, nbc*NH_), 256, 0, stream>>>(Qc, kvb, Ac);
            gemm_bf16<2><<<dim3(2, gy), 256, 0, stream>>>(Ac, owT_l, nullptr, nullptr, xc, RCn, 256, 256);
            // MLP
            ln_f2b_kernel<<<lnb, 256, 0, stream>>>(xc, n2g + layer*D_, n2b + layer*D_, Xn, RCn);
            gemm_bf16<1><<<dim3(8, gy), 256, 0, stream>>>(Xn, w1T_l, b1_l, Hc, nullptr, RCn, 1024, 256);
            gemm_bf16<3><<<dim3(2, gy), 256, 0, stream>>>(Hc, w2T_l, b2_l, nullptr, xc, RCn, 256, 1024);
        }
    }

    head_kernel<<<B_, 256, 0, stream>>>(x, obs, fng, fnb, outw, outb, (float*)d_out);
}

// Round 4
// 3361.281 us; speedup vs baseline: 5.7304x; 1.8791x over previous
//
#include <hip/hip_runtime.h>
#include <math.h>

typedef unsigned short u16;
typedef __attribute__((ext_vector_type(8))) short short8;
typedef __attribute__((ext_vector_type(4))) short short4v;
typedef __attribute__((ext_vector_type(4))) float f32x4;

// ---------------- problem constants ----------------
constexpr int B_    = 32;
constexpr int HIST_ = 10, C_ = 11, H_ = 15, W_ = 20;
constexpr int D_    = 256, NH_ = 4, NL_ = 4, HD_ = 64;
constexpr int OUT_  = 256, ADIM_ = 20;
constexpr int L_    = HIST_*H_*W_ + 1;      // 3001
constexpr int VIS_  = HIST_*C_*H_*W_;       // 33000
constexpr int NTOK  = B_*L_;                // 96032
constexpr int OBSROW = VIS_ + ADIM_;        // 33020

// ---------------- bf16 helpers ----------------
__device__ __forceinline__ float bf2f(u16 u) {
    return __uint_as_float(((unsigned)u) << 16);
}
__device__ __forceinline__ u16 f2bf(float f) {
    unsigned u = __float_as_uint(f);
    u = u + 0x7FFFu + ((u >> 16) & 1u);
    return (u16)(u >> 16);
}
__device__ __forceinline__ f32x4 mfma16(short8 a, short8 b, f32x4 c) {
    return __builtin_amdgcn_mfma_f32_16x16x32_bf16(a, b, c, 0, 0, 0);
}

// ---------------- setup kernels ----------------
__global__ void zero_kernel(float* __restrict__ p, int n) {
    int i = blockIdx.x*256 + threadIdx.x;
    if (i < n) p[i] = 0.f;
}

// dst[l][dstOff+n][k] = bf16(src[l][k][n]); dst layer stride dstLS
__global__ void wcvt_kernel(const float* __restrict__ src, u16* __restrict__ dst,
                            int Nn, int Kk, int dstLS, int dstOff) {
    int idx = blockIdx.x*256 + threadIdx.x;
    int tot = NL_*Nn*Kk;
    if (idx >= tot) return;
    int l = idx / (Nn*Kk);
    int rem = idx % (Nn*Kk);
    int n = rem / Kk, k = rem % Kk;
    dst[(size_t)l*dstLS + (size_t)(dstOff+n)*Kk + k] = f2bf(src[(size_t)l*Kk*Nn + (size_t)k*Nn + n]);
}

__global__ void rope_table_kernel(float* __restrict__ tab) {
    int idx = blockIdx.x*256 + threadIdx.x;
    if (idx >= L_*32) return;
    int t = idx >> 5, i = idx & 31;
    float freq = powf(10000.f, -2.f*(float)i/(float)HD_);
    float ang = (float)t * freq;
    tab[idx*2]   = cosf(ang);
    tab[idx*2+1] = sinf(ang);
}

__global__ void proj_kernel(const float* __restrict__ obs, const float* __restrict__ pw,
                            const float* __restrict__ pb, const float* __restrict__ cls,
                            float* __restrict__ x) {
    __shared__ float vis[C_];
    int n = blockIdx.x;
    int b = n / L_, l = n % L_;
    int d = threadIdx.x;
    float out;
    if (l == 0) {
        out = cls[d];
    } else {
        int t = l - 1;
        int hist = t / (H_*W_);
        int rem  = t % (H_*W_);
        if (d < C_) vis[d] = obs[(size_t)b*OBSROW + hist*(C_*H_*W_) + d*(H_*W_) + rem];
        __syncthreads();
        float acc = pb[d];
        #pragma unroll
        for (int c = 0; c < C_; ++c) acc += vis[c] * pw[c*D_ + d];
        out = acc;
    }
    x[(size_t)n*D_ + d] = out;
}

// ---------------- LayerNorm fp32 -> bf16 ----------------
__global__ __launch_bounds__(256) void ln_f2b_kernel(const float* __restrict__ in,
        const float* __restrict__ g, const float* __restrict__ bt,
        u16* __restrict__ out, int ntok) {
    int wave = threadIdx.x >> 6, lane = threadIdx.x & 63;
    int n = blockIdx.x*4 + wave;
    if (n >= ntok) return;
    float4 v = ((const float4*)(in + (size_t)n*D_))[lane];
    float s  = v.x + v.y + v.z + v.w;
    float sq = v.x*v.x + v.y*v.y + v.z*v.z + v.w*v.w;
    #pragma unroll
    for (int off = 32; off; off >>= 1) { s += __shfl_xor(s, off); sq += __shfl_xor(sq, off); }
    float mean = s * (1.f/D_);
    float var  = sq * (1.f/D_) - mean*mean;
    float r = rsqrtf(var + 1e-5f);
    float4 gg = ((const float4*)g)[lane];
    float4 bb = ((const float4*)bt)[lane];
    short4v o;
    o.x = (short)f2bf((v.x-mean)*r*gg.x + bb.x);
    o.y = (short)f2bf((v.y-mean)*r*gg.y + bb.y);
    o.z = (short)f2bf((v.z-mean)*r*gg.z + bb.z);
    o.w = (short)f2bf((v.w-mean)*r*gg.w + bb.w);
    *(short4v*)(out + (size_t)n*D_ + lane*4) = o;
}

// ---------------- fused LN + RoPE + SiLU (bf16 in-place, row stride ld) ----------------
__global__ __launch_bounds__(256) void lnrope_kernel(u16* __restrict__ q,
        const float* __restrict__ g, const float* __restrict__ bt,
        const float* __restrict__ tab, int ntok, int ld) {
    int wave = threadIdx.x >> 6, lane = threadIdx.x & 63;
    int n = blockIdx.x*4 + wave;
    if (n >= ntok) return;
    int l = n % L_;
    short4v raw = *(const short4v*)(q + (size_t)n*ld + lane*4);
    float v0 = bf2f((u16)raw.x), v1 = bf2f((u16)raw.y), v2 = bf2f((u16)raw.z), v3 = bf2f((u16)raw.w);
    float s  = v0+v1+v2+v3;
    float sq = v0*v0+v1*v1+v2*v2+v3*v3;
    #pragma unroll
    for (int off = 32; off; off >>= 1) { s += __shfl_xor(s, off); sq += __shfl_xor(sq, off); }
    float mean = s * (1.f/D_);
    float var  = sq * (1.f/D_) - mean*mean;
    float r = rsqrtf(var + 1e-5f);
    float4 gg = ((const float4*)g)[lane];
    float4 bb = ((const float4*)bt)[lane];
    float o0 = (v0-mean)*r*gg.x + bb.x;
    float o1 = (v1-mean)*r*gg.y + bb.y;
    float o2 = (v2-mean)*r*gg.z + bb.z;
    float o3 = (v3-mean)*r*gg.w + bb.w;
    float p0 = __shfl_xor(o0, 8), p1 = __shfl_xor(o1, 8);
    float p2 = __shfl_xor(o2, 8), p3 = __shfl_xor(o3, 8);
    bool first = (lane & 15) < 8;
    const float4* tp = (const float4*)(tab + ((size_t)l*32 + (lane&7)*4)*2);
    float4 t01 = tp[0], t23 = tp[1];
    float r0 = first ? o0*t01.x - p0*t01.y : o0*t01.x + p0*t01.y;
    float r1 = first ? o1*t01.z - p1*t01.w : o1*t01.z + p1*t01.w;
    float r2 = first ? o2*t23.x - p2*t23.y : o2*t23.x + p2*t23.y;
    float r3 = first ? o3*t23.z - p3*t23.w : o3*t23.z + p3*t23.w;
    r0 = r0 / (1.f + expf(-r0));
    r1 = r1 / (1.f + expf(-r1));
    r2 = r2 / (1.f + expf(-r2));
    r3 = r3 / (1.f + expf(-r3));
    short4v o;
    o.x = (short)f2bf(r0); o.y = (short)f2bf(r1);
    o.z = (short)f2bf(r2); o.w = (short)f2bf(r3);
    *(short4v*)(q + (size_t)n*ld + lane*4) = o;
}

// ---------------- bf16 MFMA GEMM ----------------
// C[M,N] = A[M,K] @ Wt[N,K]^T. 128x128 tile, BK=32, 4 waves. C row stride = ldc.
// EPI: 0 bf16 out; 1 +bias,GELU,bf16; 2 fp32 residual add; 3 +bias fp32 residual add
template<int EPI>
__global__ __launch_bounds__(256) void gemm_bf16(const u16* __restrict__ A,
        const u16* __restrict__ Wt, const float* __restrict__ bias,
        u16* __restrict__ Cb, float* __restrict__ Xres, int M, int N, int K, int ldc) {
    __shared__ u16 As[128][32];
    __shared__ u16 Bs[128][32];
    const int tid = threadIdx.x;
    const int row0 = blockIdx.y*128, col0 = blockIdx.x*128;
    const int wid = tid >> 6, lane = tid & 63;
    const int wr = wid >> 1, wc = wid & 1;

    f32x4 acc[4][4];
    #pragma unroll
    for (int i = 0; i < 4; ++i)
        #pragma unroll
        for (int j = 0; j < 4; ++j) {
            f32x4 z; z.x = 0.f; z.y = 0.f; z.z = 0.f; z.w = 0.f;
            acc[i][j] = z;
        }

    const int sr = tid >> 1, hf = tid & 1;
    const int sw = (sr >> 1) & 3;
    u16* ap0 = &As[sr][(((hf*2+0) ^ sw) & 3) * 8];
    u16* ap1 = &As[sr][(((hf*2+1) ^ sw) & 3) * 8];
    u16* bp0 = &Bs[sr][(((hf*2+0) ^ sw) & 3) * 8];
    u16* bp1 = &Bs[sr][(((hf*2+1) ^ sw) & 3) * 8];
    const bool arow_ok = (row0 + sr) < M;
    const u16* agp = A  + (size_t)(row0 + sr)*K + hf*16;
    const u16* bgp = Wt + (size_t)(col0 + sr)*K + hf*16;

    const int kg = lane >> 4, li = lane & 15;
    const int sidx = ((kg ^ ((li >> 1) & 3)) & 3) * 8;

    for (int k0 = 0; k0 < K; k0 += 32) {
        short8 a0 = {0,0,0,0,0,0,0,0}, a1 = {0,0,0,0,0,0,0,0};
        if (arow_ok) {
            a0 = *(const short8*)(agp + k0);
            a1 = *(const short8*)(agp + k0 + 8);
        }
        short8 b0 = *(const short8*)(bgp + k0);
        short8 b1 = *(const short8*)(bgp + k0 + 8);
        __syncthreads();
        *(short8*)ap0 = a0; *(short8*)ap1 = a1;
        *(short8*)bp0 = b0; *(short8*)bp1 = b1;
        __syncthreads();

        short8 af[4], bfr[4];
        #pragma unroll
        for (int mi = 0; mi < 4; ++mi)
            af[mi] = *(const short8*)&As[wr*64 + mi*16 + li][sidx];
        #pragma unroll
        for (int ni = 0; ni < 4; ++ni)
            bfr[ni] = *(const short8*)&Bs[wc*64 + ni*16 + li][sidx];
        #pragma unroll
        for (int mi = 0; mi < 4; ++mi)
            #pragma unroll
            for (int ni = 0; ni < 4; ++ni)
                acc[mi][ni] = mfma16(af[mi], bfr[ni], acc[mi][ni]);
    }

    #pragma unroll
    for (int mi = 0; mi < 4; ++mi) {
        int rbase = row0 + wr*64 + mi*16 + kg*4;
        #pragma unroll
        for (int ni = 0; ni < 4; ++ni) {
            int col = col0 + wc*64 + ni*16 + li;
            #pragma unroll
            for (int r = 0; r < 4; ++r) {
                int row = rbase + r;
                if (row >= M) continue;
                float v = acc[mi][ni][r];
                if (EPI == 1) { v += bias[col]; v = 0.5f*v*(1.f + erff(v*0.70710678118654752f)); }
                if (EPI == 3) { v += bias[col]; }
                if (EPI == 0 || EPI == 1) Cb[(size_t)row*ldc + col] = f2bf(v);
                else                      Xres[(size_t)row*ldc + col] += v;
            }
        }
    }
}

// ---------------- kv += K^T V per (b,h), L-chunked, fp32 atomic accum ----------------
constexpr int KV_ROWS = 128;
constexpr int KV_NCHK = (L_ + KV_ROWS - 1)/KV_ROWS;  // 24
__global__ __launch_bounds__(256) void kv_kernel(const u16* __restrict__ Kt,
        const u16* __restrict__ Vt, float* __restrict__ kvf, int ld) {
    __shared__ float ks[16][64], vs[16][64];
    int bh = blockIdx.x;
    int b = bh >> 2, h = bh & 3;
    int tid = threadIdx.x;
    int td = tid >> 4, te = tid & 15;
    int sr = tid >> 4, sc0 = (tid & 15)*4;
    float acc[4][4] = {};
    int l0 = blockIdx.y * KV_ROWS;
    int lend = min(l0 + KV_ROWS, L_);
    for (int lb = l0; lb < lend; lb += 16) {
        bool ok = (lb + sr) < lend;
        size_t gi = ((size_t)b*L_ + lb + sr)*ld + h*HD_ + sc0;
        if (ok) {
            short4v kk = *(const short4v*)(Kt + gi);
            short4v vv = *(const short4v*)(Vt + gi);
            ks[sr][sc0+0] = bf2f((u16)kk.x); ks[sr][sc0+1] = bf2f((u16)kk.y);
            ks[sr][sc0+2] = bf2f((u16)kk.z); ks[sr][sc0+3] = bf2f((u16)kk.w);
            vs[sr][sc0+0] = bf2f((u16)vv.x); vs[sr][sc0+1] = bf2f((u16)vv.y);
            vs[sr][sc0+2] = bf2f((u16)vv.z); vs[sr][sc0+3] = bf2f((u16)vv.w);
        } else {
            ks[sr][sc0+0]=0.f; ks[sr][sc0+1]=0.f; ks[sr][sc0+2]=0.f; ks[sr][sc0+3]=0.f;
            vs[sr][sc0+0]=0.f; vs[sr][sc0+1]=0.f; vs[sr][sc0+2]=0.f; vs[sr][sc0+3]=0.f;
        }
        __syncthreads();
        #pragma unroll
        for (int r = 0; r < 16; ++r) {
            float a0 = ks[r][td*4+0], a1 = ks[r][td*4+1], a2 = ks[r][td*4+2], a3 = ks[r][td*4+3];
            float4 bv = *(const float4*)&vs[r][te*4];
            acc[0][0] += a0*bv.x; acc[0][1] += a0*bv.y; acc[0][2] += a0*bv.z; acc[0][3] += a0*bv.w;
            acc[1][0] += a1*bv.x; acc[1][1] += a1*bv.y; acc[1][2] += a1*bv.z; acc[1][3] += a1*bv.w;
            acc[2][0] += a2*bv.x; acc[2][1] += a2*bv.y; acc[2][2] += a2*bv.z; acc[2][3] += a2*bv.w;
            acc[3][0] += a3*bv.x; acc[3][1] += a3*bv.y; acc[3][2] += a3*bv.z; acc[3][3] += a3*bv.w;
        }
        __syncthreads();
    }
    float* base = kvf + (size_t)bh*4096;
    #pragma unroll
    for (int i = 0; i < 4; ++i)
        #pragma unroll
        for (int j = 0; j < 4; ++j)
            atomicAdd(base + (td*4+i)*64 + te*4+j, acc[i][j]);
}

// ---------------- attn: out = Q @ kv / 8 (kv fp32) ----------------
constexpr int ATT_NTL = (L_ + 63) / 64;  // 47
__global__ __launch_bounds__(256) void attn_kernel(const u16* __restrict__ Q,
        const float* __restrict__ kvf, u16* __restrict__ Aout, int ld) {
    __shared__ float qT[64][65];
    __shared__ float km[64][64];
    int tl = blockIdx.x;
    int bh = blockIdx.y;
    int b = bh >> 2, h = bh & 3;
    int tid = threadIdx.x;
    int l0 = tl*64;
    #pragma unroll
    for (int p = 0; p < 16; ++p) {
        int lin = p*256 + tid;
        ((float*)km)[lin] = kvf[(size_t)bh*4096 + lin];
    }
    #pragma unroll
    for (int p = 0; p < 4; ++p) {
        int u = p*256 + tid;
        int r = u >> 4, c0 = (u & 15)*4;
        int l = l0 + r;
        if (l < L_) {
            short4v qq = *(const short4v*)(Q + ((size_t)b*L_ + l)*ld + h*HD_ + c0);
            qT[c0+0][r] = bf2f((u16)qq.x); qT[c0+1][r] = bf2f((u16)qq.y);
            qT[c0+2][r] = bf2f((u16)qq.z); qT[c0+3][r] = bf2f((u16)qq.w);
        } else {
            qT[c0+0][r]=0.f; qT[c0+1][r]=0.f; qT[c0+2][r]=0.f; qT[c0+3][r]=0.f;
        }
    }
    __syncthreads();
    int ty = tid >> 4, tx = tid & 15;
    float acc[4][4] = {};
    for (int k = 0; k < 64; ++k) {
        float a0 = qT[k][ty*4+0], a1 = qT[k][ty*4+1], a2 = qT[k][ty*4+2], a3 = qT[k][ty*4+3];
        float4 bv = *(const float4*)&km[k][tx*4];
        acc[0][0] += a0*bv.x; acc[0][1] += a0*bv.y; acc[0][2] += a0*bv.z; acc[0][3] += a0*bv.w;
        acc[1][0] += a1*bv.x; acc[1][1] += a1*bv.y; acc[1][2] += a1*bv.z; acc[1][3] += a1*bv.w;
        acc[2][0] += a2*bv.x; acc[2][1] += a2*bv.y; acc[2][2] += a2*bv.z; acc[2][3] += a2*bv.w;
        acc[3][0] += a3*bv.x; acc[3][1] += a3*bv.y; acc[3][2] += a3*bv.z; acc[3][3] += a3*bv.w;
    }
    #pragma unroll
    for (int i = 0; i < 4; ++i) {
        int l = l0 + ty*4 + i;
        if (l >= L_) continue;
        short4v o;
        o.x = (short)f2bf(acc[i][0]*0.125f); o.y = (short)f2bf(acc[i][1]*0.125f);
        o.z = (short)f2bf(acc[i][2]*0.125f); o.w = (short)f2bf(acc[i][3]*0.125f);
        *(short4v*)(Aout + ((size_t)b*L_ + l)*D_ + h*HD_ + tx*4) = o;
    }
}

// ---------------- head ----------------
__global__ void head_kernel(const float* __restrict__ x, const float* __restrict__ obs,
                            const float* __restrict__ fng, const float* __restrict__ fnb,
                            const float* __restrict__ ow, const float* __restrict__ ob,
                            float* __restrict__ out) {
    __shared__ float row[D_ + ADIM_];
    __shared__ float red[8];
    int b = blockIdx.x, tid = threadIdx.x;
    float v = x[((size_t)b*L_)*D_ + tid];
    float s = v, sq = v*v;
    #pragma unroll
    for (int off = 32; off; off >>= 1) { s += __shfl_xor(s, off); sq += __shfl_xor(sq, off); }
    int wave = tid >> 6, lane = tid & 63;
    if (lane == 0) { red[wave] = s; red[4+wave] = sq; }
    __syncthreads();
    s  = red[0]+red[1]+red[2]+red[3];
    sq = red[4]+red[5]+red[6]+red[7];
    float mean = s*(1.f/D_), var = sq*(1.f/D_) - mean*mean;
    float r = rsqrtf(var + 1e-5f);
    row[tid] = (v-mean)*r*fng[tid] + fnb[tid];
    if (tid < ADIM_) row[D_+tid] = obs[(size_t)b*OBSROW + VIS_ + tid];
    __syncthreads();
    float acc = ob[tid];
    for (int j = 0; j < D_+ADIM_; ++j) acc += row[j]*ow[j*OUT_ + tid];
    out[(size_t)b*OUT_ + tid] = acc;
}

// ---------------- launch ----------------
extern "C" void kernel_launch(void* const* d_in, const int* in_sizes, int n_in,
                              void* d_out, int out_size, void* d_ws, size_t ws_size,
                              hipStream_t stream) {
    const float* obs   = (const float*)d_in[0];
    const float* pw    = (const float*)d_in[1];
    const float* pb    = (const float*)d_in[2];
    const float* cls   = (const float*)d_in[3];
    const float* qw    = (const float*)d_in[4];
    const float* kw    = (const float*)d_in[5];
    const float* vw    = (const float*)d_in[6];
    const float* oww   = (const float*)d_in[7];
    const float* gq    = (const float*)d_in[8];
    const float* bq    = (const float*)d_in[9];
    const float* gk    = (const float*)d_in[10];
    const float* bk    = (const float*)d_in[11];
    const float* n1g   = (const float*)d_in[12];
    const float* n1b   = (const float*)d_in[13];
    const float* n2g   = (const float*)d_in[14];
    const float* n2b   = (const float*)d_in[15];
    const float* w1    = (const float*)d_in[16];
    const float* b1    = (const float*)d_in[17];
    const float* w2    = (const float*)d_in[18];
    const float* b2    = (const float*)d_in[19];
    const float* fng   = (const float*)d_in[20];
    const float* fnb   = (const float*)d_in[21];
    const float* outw  = (const float*)d_in[22];
    const float* outb  = (const float*)d_in[23];

    // ---- workspace layout ----
    float* x = (float*)d_ws;                               // NTOK*256 fp32
    u16* qkvT = (u16*)(x + (size_t)NTOK*D_);               // [NL][768][256]
    u16* owT  = qkvT + (size_t)NL_*768*256;                // [NL][256][256]
    u16* w1T  = owT  + (size_t)NL_*65536;                  // [NL][1024][256]
    u16* w2T  = w1T  + (size_t)NL_*262144;                 // [NL][256][1024]
    float* tab = (float*)(w2T + (size_t)NL_*262144);       // L*32*2 fp32
    u16* bufs = (u16*)(tab + (size_t)L_*32*2);

    size_t fixedB = (size_t)((char*)bufs - (char*)d_ws);
    auto needed = [&](int nb) -> size_t {
        size_t ch = (size_t)nb * L_ * D_;
        return fixedB + ch*5*2 + (size_t)nb*NH_*4096*4;
    };
    int nbc = 32;
    while (nbc > 1 && needed(nbc) > ws_size) nbc >>= 1;
    const int nch = B_ / nbc;
    const int RCn = nbc * L_;
    const size_t CH = (size_t)nbc * L_ * D_;

    u16* Xn   = bufs;            // CH
    u16* QKVc = Xn + CH;         // 3*CH, row stride 768 (Q|K|V)
    u16* Ac   = QKVc + 3*CH;     // CH
    u16* Hc   = QKVc;            // alias: MLP hidden = 4*CH exactly
    float* kvf = (float*)(Ac + CH);   // nbc*4*4096 fp32

    // ---- setup ----
    wcvt_kernel<<<(NL_*65536 + 255)/256, 256, 0, stream>>>(qw,  qkvT, 256, 256, 768*256, 0);
    wcvt_kernel<<<(NL_*65536 + 255)/256, 256, 0, stream>>>(kw,  qkvT, 256, 256, 768*256, 256);
    wcvt_kernel<<<(NL_*65536 + 255)/256, 256, 0, stream>>>(vw,  qkvT, 256, 256, 768*256, 512);
    wcvt_kernel<<<(NL_*65536 + 255)/256, 256, 0, stream>>>(oww, owT, 256, 256, 65536, 0);
    wcvt_kernel<<<(NL_*262144 + 255)/256, 256, 0, stream>>>(w1, w1T, 1024, 256, 262144, 0);
    wcvt_kernel<<<(NL_*262144 + 255)/256, 256, 0, stream>>>(w2, w2T, 256, 1024, 262144, 0);
    rope_table_kernel<<<(L_*32 + 255)/256, 256, 0, stream>>>(tab);
    proj_kernel<<<NTOK, 256, 0, stream>>>(obs, pw, pb, cls, x);

    const int gy  = (RCn + 127)/128;
    const int lnb = (RCn + 3)/4;
    const int nbh = nbc*NH_;

    for (int layer = 0; layer < NL_; ++layer) {
        const u16* qkvT_l = qkvT + (size_t)layer*768*256;
        const u16* owT_l  = owT  + (size_t)layer*65536;
        const u16* w1T_l  = w1T  + (size_t)layer*262144;
        const u16* w2T_l  = w2T  + (size_t)layer*262144;
        const float* b1_l = b1 + (size_t)layer*1024;
        const float* b2_l = b2 + (size_t)layer*D_;

        for (int c = 0; c < nch; ++c) {
            float* xc = x + (size_t)c*RCn*D_;
            ln_f2b_kernel<<<lnb, 256, 0, stream>>>(xc, n1g + layer*D_, n1b + layer*D_, Xn, RCn);
            gemm_bf16<0><<<dim3(6, gy), 256, 0, stream>>>(Xn, qkvT_l, nullptr, QKVc, nullptr, RCn, 768, 256, 768);
            lnrope_kernel<<<lnb, 256, 0, stream>>>(QKVc,       gq + layer*D_, bq + layer*D_, tab, RCn, 768);
            lnrope_kernel<<<lnb, 256, 0, stream>>>(QKVc + 256, gk + layer*D_, bk + layer*D_, tab, RCn, 768);
            zero_kernel<<<(nbh*4096 + 255)/256, 256, 0, stream>>>(kvf, nbh*4096);
            kv_kernel<<<dim3(nbh, KV_NCHK), 256, 0, stream>>>(QKVc + 256, QKVc + 512, kvf, 768);
            attn_kernel<<<dim3(ATT_NTL, nbh), 256, 0, stream>>>(QKVc, kvf, Ac, 768);
            gemm_bf16<2><<<dim3(2, gy), 256, 0, stream>>>(Ac, owT_l, nullptr, nullptr, xc, RCn, 256, 256, 256);
            // MLP (hidden aliases QKVc..Ac, all dead by now)
            ln_f2b_kernel<<<lnb, 256, 0, stream>>>(xc, n2g + layer*D_, n2b + layer*D_, Xn, RCn);
            gemm_bf16<1><<<dim3(8, gy), 256, 0, stream>>>(Xn, w1T_l, b1_l, Hc, nullptr, RCn, 1024, 256, 1024);
            gemm_bf16<3><<<dim3(2, gy), 256, 0, stream>>>(Hc, w2T_l, b2_l, nullptr, xc, RCn, 256, 1024, 256);
        }
    }

    head_kernel<<<B_, 256, 0, stream>>>(x, obs, fng, fnb, outw, outb, (float*)d_out);
}

// Round 5
// 3045.767 us; speedup vs baseline: 6.3240x; 1.1036x over previous
//
#include <hip/hip_runtime.h>
#include <math.h>

typedef unsigned short u16;
typedef __attribute__((ext_vector_type(8))) short short8;
typedef __attribute__((ext_vector_type(4))) short short4v;
typedef __attribute__((ext_vector_type(4))) float f32x4;

// ---------------- problem constants ----------------
constexpr int B_    = 32;
constexpr int HIST_ = 10, C_ = 11, H_ = 15, W_ = 20;
constexpr int D_    = 256, NH_ = 4, NL_ = 4, HD_ = 64;
constexpr int OUT_  = 256, ADIM_ = 20;
constexpr int L_    = HIST_*H_*W_ + 1;      // 3001
constexpr int VIS_  = HIST_*C_*H_*W_;       // 33000
constexpr int NTOK  = B_*L_;                // 96032
constexpr int OBSROW = VIS_ + ADIM_;        // 33020
constexpr int PADR  = 112;                  // extra rows so DMA reads stay in-bounds

// ---------------- bf16 helpers ----------------
__device__ __forceinline__ float bf2f(u16 u) {
    return __uint_as_float(((unsigned)u) << 16);
}
__device__ __forceinline__ u16 f2bf(float f) {
    unsigned u = __float_as_uint(f);
    u = u + 0x7FFFu + ((u >> 16) & 1u);
    return (u16)(u >> 16);
}
__device__ __forceinline__ f32x4 mfma16(short8 a, short8 b, f32x4 c) {
    return __builtin_amdgcn_mfma_f32_16x16x32_bf16(a, b, c, 0, 0, 0);
}
__device__ __forceinline__ void gload16(const u16* gsrc, u16* ldsdst) {
    __builtin_amdgcn_global_load_lds(
        (const __attribute__((address_space(1))) unsigned int*)gsrc,
        (__attribute__((address_space(3))) unsigned int*)ldsdst,
        16, 0, 0);
}

// ---------------- setup kernels ----------------
__global__ void zero_kernel(float* __restrict__ p, int n) {
    int i = blockIdx.x*256 + threadIdx.x;
    if (i < n) p[i] = 0.f;
}

// dst[l][dstOff+n][k] = bf16(src[l][k][n]); dst layer stride dstLS
__global__ void wcvt_kernel(const float* __restrict__ src, u16* __restrict__ dst,
                            int Nn, int Kk, int dstLS, int dstOff) {
    int idx = blockIdx.x*256 + threadIdx.x;
    int tot = NL_*Nn*Kk;
    if (idx >= tot) return;
    int l = idx / (Nn*Kk);
    int rem = idx % (Nn*Kk);
    int n = rem / Kk, k = rem % Kk;
    dst[(size_t)l*dstLS + (size_t)(dstOff+n)*Kk + k] = f2bf(src[(size_t)l*Kk*Nn + (size_t)k*Nn + n]);
}

__global__ void rope_table_kernel(float* __restrict__ tab) {
    int idx = blockIdx.x*256 + threadIdx.x;
    if (idx >= L_*32) return;
    int t = idx >> 5, i = idx & 31;
    float freq = powf(10000.f, -2.f*(float)i/(float)HD_);
    float ang = (float)t * freq;
    tab[idx*2]   = cosf(ang);
    tab[idx*2+1] = sinf(ang);
}

__global__ void proj_kernel(const float* __restrict__ obs, const float* __restrict__ pw,
                            const float* __restrict__ pb, const float* __restrict__ cls,
                            float* __restrict__ x) {
    __shared__ float vis[C_];
    int n = blockIdx.x;
    int b = n / L_, l = n % L_;
    int d = threadIdx.x;
    float out;
    if (l == 0) {
        out = cls[d];
    } else {
        int t = l - 1;
        int hist = t / (H_*W_);
        int rem  = t % (H_*W_);
        if (d < C_) vis[d] = obs[(size_t)b*OBSROW + hist*(C_*H_*W_) + d*(H_*W_) + rem];
        __syncthreads();
        float acc = pb[d];
        #pragma unroll
        for (int c = 0; c < C_; ++c) acc += vis[c] * pw[c*D_ + d];
        out = acc;
    }
    x[(size_t)n*D_ + d] = out;
}

// ---------------- LayerNorm fp32 -> bf16 ----------------
__global__ __launch_bounds__(256) void ln_f2b_kernel(const float* __restrict__ in,
        const float* __restrict__ g, const float* __restrict__ bt,
        u16* __restrict__ out, int ntok) {
    int wave = threadIdx.x >> 6, lane = threadIdx.x & 63;
    int n = blockIdx.x*4 + wave;
    if (n >= ntok) return;
    float4 v = ((const float4*)(in + (size_t)n*D_))[lane];
    float s  = v.x + v.y + v.z + v.w;
    float sq = v.x*v.x + v.y*v.y + v.z*v.z + v.w*v.w;
    #pragma unroll
    for (int off = 32; off; off >>= 1) { s += __shfl_xor(s, off); sq += __shfl_xor(sq, off); }
    float mean = s * (1.f/D_);
    float var  = sq * (1.f/D_) - mean*mean;
    float r = rsqrtf(var + 1e-5f);
    float4 gg = ((const float4*)g)[lane];
    float4 bb = ((const float4*)bt)[lane];
    short4v o;
    o.x = (short)f2bf((v.x-mean)*r*gg.x + bb.x);
    o.y = (short)f2bf((v.y-mean)*r*gg.y + bb.y);
    o.z = (short)f2bf((v.z-mean)*r*gg.z + bb.z);
    o.w = (short)f2bf((v.w-mean)*r*gg.w + bb.w);
    *(short4v*)(out + (size_t)n*D_ + lane*4) = o;
}

// ---------------- fused LN + RoPE + SiLU (bf16 in-place, row stride ld) ----------------
__global__ __launch_bounds__(256) void lnrope_kernel(u16* __restrict__ q,
        const float* __restrict__ g, const float* __restrict__ bt,
        const float* __restrict__ tab, int ntok, int ld) {
    int wave = threadIdx.x >> 6, lane = threadIdx.x & 63;
    int n = blockIdx.x*4 + wave;
    if (n >= ntok) return;
    int l = n % L_;
    short4v raw = *(const short4v*)(q + (size_t)n*ld + lane*4);
    float v0 = bf2f((u16)raw.x), v1 = bf2f((u16)raw.y), v2 = bf2f((u16)raw.z), v3 = bf2f((u16)raw.w);
    float s  = v0+v1+v2+v3;
    float sq = v0*v0+v1*v1+v2*v2+v3*v3;
    #pragma unroll
    for (int off = 32; off; off >>= 1) { s += __shfl_xor(s, off); sq += __shfl_xor(sq, off); }
    float mean = s * (1.f/D_);
    float var  = sq * (1.f/D_) - mean*mean;
    float r = rsqrtf(var + 1e-5f);
    float4 gg = ((const float4*)g)[lane];
    float4 bb = ((const float4*)bt)[lane];
    float o0 = (v0-mean)*r*gg.x + bb.x;
    float o1 = (v1-mean)*r*gg.y + bb.y;
    float o2 = (v2-mean)*r*gg.z + bb.z;
    float o3 = (v3-mean)*r*gg.w + bb.w;
    float p0 = __shfl_xor(o0, 8), p1 = __shfl_xor(o1, 8);
    float p2 = __shfl_xor(o2, 8), p3 = __shfl_xor(o3, 8);
    bool first = (lane & 15) < 8;
    const float4* tp = (const float4*)(tab + ((size_t)l*32 + (lane&7)*4)*2);
    float4 t01 = tp[0], t23 = tp[1];
    float r0 = first ? o0*t01.x - p0*t01.y : o0*t01.x + p0*t01.y;
    float r1 = first ? o1*t01.z - p1*t01.w : o1*t01.z + p1*t01.w;
    float r2 = first ? o2*t23.x - p2*t23.y : o2*t23.x + p2*t23.y;
    float r3 = first ? o3*t23.z - p3*t23.w : o3*t23.z + p3*t23.w;
    r0 = r0 / (1.f + expf(-r0));
    r1 = r1 / (1.f + expf(-r1));
    r2 = r2 / (1.f + expf(-r2));
    r3 = r3 / (1.f + expf(-r3));
    short4v o;
    o.x = (short)f2bf(r0); o.y = (short)f2bf(r1);
    o.z = (short)f2bf(r2); o.w = (short)f2bf(r3);
    *(short4v*)(q + (size_t)n*ld + lane*4) = o;
}

// ---------------- bf16 MFMA GEMM, global_load_lds staging ----------------
// C[M,N] = A[M,K] @ Wt[N,K]^T. 128x128 tile, BK=32, 4 waves (2x2), 16x16x32 MFMA.
// LDS linear [128][32] with rotate-swizzle: stored slot s' = (s + (row>>1))&3
// (s = logical 8-elem k-slot), applied by pre-swizzling the GLOBAL source addr.
// A rows [M, M+PADR) may be read (garbage) — caller must pad; C-write is guarded.
// EPI: 0 bf16 out; 1 +bias,GELU,bf16; 2 fp32 residual add; 3 +bias fp32 residual add
template<int EPI>
__global__ __launch_bounds__(256) void gemm_bf16(const u16* __restrict__ A,
        const u16* __restrict__ Wt, const float* __restrict__ bias,
        u16* __restrict__ Cb, float* __restrict__ Xres, int M, int N, int K, int ldc) {
    __shared__ u16 As[128*32];
    __shared__ u16 Bs[128*32];
    // XCD-chunked block remap: each XCD gets a contiguous band of row-tiles
    const int gx = gridDim.x;
    int n = blockIdx.y * gx + blockIdx.x;
    const int nwg = gx * gridDim.y;
    if ((nwg & 7) == 0) n = (n & 7) * (nwg >> 3) + (n >> 3);
    const int bx = n % gx, by = n / gx;
    const int row0 = by*128, col0 = bx*128;

    const int tid = threadIdx.x;
    const int wid = tid >> 6, lane = tid & 63;
    const int wr = wid >> 1, wc = wid & 1;

    f32x4 acc[4][4];
    #pragma unroll
    for (int i = 0; i < 4; ++i)
        #pragma unroll
        for (int j = 0; j < 4; ++j) {
            f32x4 z; z.x = 0.f; z.y = 0.f; z.z = 0.f; z.w = 0.f;
            acc[i][j] = z;
        }

    // DMA staging: instruction i in {0,1} per matrix per wave covers LDS bytes
    // [(wid*2+i)*1024, +1024); lane l -> row r=(wid*2+i)*16+(l>>2), stored slot l&3.
    const int r0s = wid*32 + (lane>>2);
    const int r1s = r0s + 16;
    const int s0 = ((lane&3) - (r0s>>1)) & 3;   // logical k-slot staged at this pos
    const int s1 = ((lane&3) - (r1s>>1)) & 3;
    const u16* a0p = A  + (size_t)(row0 + r0s)*K + s0*8;
    const u16* a1p = A  + (size_t)(row0 + r1s)*K + s1*8;
    const u16* b0p = Wt + (size_t)(col0 + r0s)*K + s0*8;
    const u16* b1p = Wt + (size_t)(col0 + r1s)*K + s1*8;
    u16* lA0 = As + (wid*2+0)*512;
    u16* lA1 = As + (wid*2+1)*512;
    u16* lB0 = Bs + (wid*2+0)*512;
    u16* lB1 = Bs + (wid*2+1)*512;

    // fragment read offsets (swizzled): row*32 + ((kg + (row>>1))&3)*8
    const int kg = lane >> 4, li = lane & 15;
    int aoff[4], boff[4];
    #pragma unroll
    for (int mi = 0; mi < 4; ++mi) {
        int row = wr*64 + mi*16 + li;
        aoff[mi] = row*32 + ((kg + (row>>1)) & 3)*8;
    }
    #pragma unroll
    for (int ni = 0; ni < 4; ++ni) {
        int row = wc*64 + ni*16 + li;
        boff[ni] = row*32 + ((kg + (row>>1)) & 3)*8;
    }

    // prologue: stage k-tile 0
    gload16(a0p, lA0); gload16(a1p, lA1);
    gload16(b0p, lB0); gload16(b1p, lB1);

    const int nk = K >> 5;
    for (int ks = 0; ks < nk; ++ks) {
        __syncthreads();                    // DMA for this tile complete (vmcnt drain)
        short8 af[4], bfr[4];
        #pragma unroll
        for (int mi = 0; mi < 4; ++mi) af[mi] = *(const short8*)(As + aoff[mi]);
        #pragma unroll
        for (int ni = 0; ni < 4; ++ni) bfr[ni] = *(const short8*)(Bs + boff[ni]);
        __syncthreads();                    // frags in regs; LDS safe to overwrite
        if (ks + 1 < nk) {
            const int k0 = (ks + 1) << 5;   // DMA next tile under the MFMAs
            gload16(a0p + k0, lA0); gload16(a1p + k0, lA1);
            gload16(b0p + k0, lB0); gload16(b1p + k0, lB1);
        }
        #pragma unroll
        for (int mi = 0; mi < 4; ++mi)
            #pragma unroll
            for (int ni = 0; ni < 4; ++ni)
                acc[mi][ni] = mfma16(af[mi], bfr[ni], acc[mi][ni]);
    }

    #pragma unroll
    for (int mi = 0; mi < 4; ++mi) {
        int rbase = row0 + wr*64 + mi*16 + kg*4;
        #pragma unroll
        for (int ni = 0; ni < 4; ++ni) {
            int col = col0 + wc*64 + ni*16 + li;
            #pragma unroll
            for (int r = 0; r < 4; ++r) {
                int row = rbase + r;
                if (row >= M) continue;
                float v = acc[mi][ni][r];
                if (EPI == 1) { v += bias[col]; v = 0.5f*v*(1.f + erff(v*0.70710678118654752f)); }
                if (EPI == 3) { v += bias[col]; }
                if (EPI == 0 || EPI == 1) Cb[(size_t)row*ldc + col] = f2bf(v);
                else                      Xres[(size_t)row*ldc + col] += v;
            }
        }
    }
}

// ---------------- kv += K^T V per (b,h), L-chunked, fp32 atomic accum ----------------
constexpr int KV_ROWS = 128;
constexpr int KV_NCHK = (L_ + KV_ROWS - 1)/KV_ROWS;  // 24
__global__ __launch_bounds__(256) void kv_kernel(const u16* __restrict__ Kt,
        const u16* __restrict__ Vt, float* __restrict__ kvf, int ld) {
    __shared__ float ks[16][64], vs[16][64];
    int bh = blockIdx.x;
    int b = bh >> 2, h = bh & 3;
    int tid = threadIdx.x;
    int td = tid >> 4, te = tid & 15;
    int sr = tid >> 4, sc0 = (tid & 15)*4;
    float acc[4][4] = {};
    int l0 = blockIdx.y * KV_ROWS;
    int lend = min(l0 + KV_ROWS, L_);
    for (int lb = l0; lb < lend; lb += 16) {
        bool ok = (lb + sr) < lend;
        size_t gi = ((size_t)b*L_ + lb + sr)*ld + h*HD_ + sc0;
        if (ok) {
            short4v kk = *(const short4v*)(Kt + gi);
            short4v vv = *(const short4v*)(Vt + gi);
            ks[sr][sc0+0] = bf2f((u16)kk.x); ks[sr][sc0+1] = bf2f((u16)kk.y);
            ks[sr][sc0+2] = bf2f((u16)kk.z); ks[sr][sc0+3] = bf2f((u16)kk.w);
            vs[sr][sc0+0] = bf2f((u16)vv.x); vs[sr][sc0+1] = bf2f((u16)vv.y);
            vs[sr][sc0+2] = bf2f((u16)vv.z); vs[sr][sc0+3] = bf2f((u16)vv.w);
        } else {
            ks[sr][sc0+0]=0.f; ks[sr][sc0+1]=0.f; ks[sr][sc0+2]=0.f; ks[sr][sc0+3]=0.f;
            vs[sr][sc0+0]=0.f; vs[sr][sc0+1]=0.f; vs[sr][sc0+2]=0.f; vs[sr][sc0+3]=0.f;
        }
        __syncthreads();
        #pragma unroll
        for (int r = 0; r < 16; ++r) {
            float a0 = ks[r][td*4+0], a1 = ks[r][td*4+1], a2 = ks[r][td*4+2], a3 = ks[r][td*4+3];
            float4 bv = *(const float4*)&vs[r][te*4];
            acc[0][0] += a0*bv.x; acc[0][1] += a0*bv.y; acc[0][2] += a0*bv.z; acc[0][3] += a0*bv.w;
            acc[1][0] += a1*bv.x; acc[1][1] += a1*bv.y; acc[1][2] += a1*bv.z; acc[1][3] += a1*bv.w;
            acc[2][0] += a2*bv.x; acc[2][1] += a2*bv.y; acc[2][2] += a2*bv.z; acc[2][3] += a2*bv.w;
            acc[3][0] += a3*bv.x; acc[3][1] += a3*bv.y; acc[3][2] += a3*bv.z; acc[3][3] += a3*bv.w;
        }
        __syncthreads();
    }
    float* base = kvf + (size_t)bh*4096;
    #pragma unroll
    for (int i = 0; i < 4; ++i)
        #pragma unroll
        for (int j = 0; j < 4; ++j)
            atomicAdd(base + (td*4+i)*64 + te*4+j, acc[i][j]);
}

// ---------------- attn: out = Q @ kv / 8 (kv fp32) ----------------
constexpr int ATT_NTL = (L_ + 63) / 64;  // 47
__global__ __launch_bounds__(256) void attn_kernel(const u16* __restrict__ Q,
        const float* __restrict__ kvf, u16* __restrict__ Aout, int ld) {
    __shared__ float qT[64][65];
    __shared__ float km[64][64];
    int tl = blockIdx.x;
    int bh = blockIdx.y;
    int b = bh >> 2, h = bh & 3;
    int tid = threadIdx.x;
    int l0 = tl*64;
    #pragma unroll
    for (int p = 0; p < 16; ++p) {
        int lin = p*256 + tid;
        ((float*)km)[lin] = kvf[(size_t)bh*4096 + lin];
    }
    #pragma unroll
    for (int p = 0; p < 4; ++p) {
        int u = p*256 + tid;
        int r = u >> 4, c0 = (u & 15)*4;
        int l = l0 + r;
        if (l < L_) {
            short4v qq = *(const short4v*)(Q + ((size_t)b*L_ + l)*ld + h*HD_ + c0);
            qT[c0+0][r] = bf2f((u16)qq.x); qT[c0+1][r] = bf2f((u16)qq.y);
            qT[c0+2][r] = bf2f((u16)qq.z); qT[c0+3][r] = bf2f((u16)qq.w);
        } else {
            qT[c0+0][r]=0.f; qT[c0+1][r]=0.f; qT[c0+2][r]=0.f; qT[c0+3][r]=0.f;
        }
    }
    __syncthreads();
    int ty = tid >> 4, tx = tid & 15;
    float acc[4][4] = {};
    for (int k = 0; k < 64; ++k) {
        float a0 = qT[k][ty*4+0], a1 = qT[k][ty*4+1], a2 = qT[k][ty*4+2], a3 = qT[k][ty*4+3];
        float4 bv = *(const float4*)&km[k][tx*4];
        acc[0][0] += a0*bv.x; acc[0][1] += a0*bv.y; acc[0][2] += a0*bv.z; acc[0][3] += a0*bv.w;
        acc[1][0] += a1*bv.x; acc[1][1] += a1*bv.y; acc[1][2] += a1*bv.z; acc[1][3] += a1*bv.w;
        acc[2][0] += a2*bv.x; acc[2][1] += a2*bv.y; acc[2][2] += a2*bv.z; acc[2][3] += a2*bv.w;
        acc[3][0] += a3*bv.x; acc[3][1] += a3*bv.y; acc[3][2] += a3*bv.z; acc[3][3] += a3*bv.w;
    }
    #pragma unroll
    for (int i = 0; i < 4; ++i) {
        int l = l0 + ty*4 + i;
        if (l >= L_) continue;
        short4v o;
        o.x = (short)f2bf(acc[i][0]*0.125f); o.y = (short)f2bf(acc[i][1]*0.125f);
        o.z = (short)f2bf(acc[i][2]*0.125f); o.w = (short)f2bf(acc[i][3]*0.125f);
        *(short4v*)(Aout + ((size_t)b*L_ + l)*D_ + h*HD_ + tx*4) = o;
    }
}

// ---------------- head ----------------
__global__ void head_kernel(const float* __restrict__ x, const float* __restrict__ obs,
                            const float* __restrict__ fng, const float* __restrict__ fnb,
                            const float* __restrict__ ow, const float* __restrict__ ob,
                            float* __restrict__ out) {
    __shared__ float row[D_ + ADIM_];
    __shared__ float red[8];
    int b = blockIdx.x, tid = threadIdx.x;
    float v = x[((size_t)b*L_)*D_ + tid];
    float s = v, sq = v*v;
    #pragma unroll
    for (int off = 32; off; off >>= 1) { s += __shfl_xor(s, off); sq += __shfl_xor(sq, off); }
    int wave = tid >> 6, lane = tid & 63;
    if (lane == 0) { red[wave] = s; red[4+wave] = sq; }
    __syncthreads();
    s  = red[0]+red[1]+red[2]+red[3];
    sq = red[4]+red[5]+red[6]+red[7];
    float mean = s*(1.f/D_), var = sq*(1.f/D_) - mean*mean;
    float r = rsqrtf(var + 1e-5f);
    row[tid] = (v-mean)*r*fng[tid] + fnb[tid];
    if (tid < ADIM_) row[D_+tid] = obs[(size_t)b*OBSROW + VIS_ + tid];
    __syncthreads();
    float acc = ob[tid];
    for (int j = 0; j < D_+ADIM_; ++j) acc += row[j]*ow[j*OUT_ + tid];
    out[(size_t)b*OUT_ + tid] = acc;
}

// ---------------- launch ----------------
extern "C" void kernel_launch(void* const* d_in, const int* in_sizes, int n_in,
                              void* d_out, int out_size, void* d_ws, size_t ws_size,
                              hipStream_t stream) {
    const float* obs   = (const float*)d_in[0];
    const float* pw    = (const float*)d_in[1];
    const float* pb    = (const float*)d_in[2];
    const float* cls   = (const float*)d_in[3];
    const float* qw    = (const float*)d_in[4];
    const float* kw    = (const float*)d_in[5];
    const float* vw    = (const float*)d_in[6];
    const float* oww   = (const float*)d_in[7];
    const float* gq    = (const float*)d_in[8];
    const float* bq    = (const float*)d_in[9];
    const float* gk    = (const float*)d_in[10];
    const float* bk    = (const float*)d_in[11];
    const float* n1g   = (const float*)d_in[12];
    const float* n1b   = (const float*)d_in[13];
    const float* n2g   = (const float*)d_in[14];
    const float* n2b   = (const float*)d_in[15];
    const float* w1    = (const float*)d_in[16];
    const float* b1    = (const float*)d_in[17];
    const float* w2    = (const float*)d_in[18];
    const float* b2    = (const float*)d_in[19];
    const float* fng   = (const float*)d_in[20];
    const float* fnb   = (const float*)d_in[21];
    const float* outw  = (const float*)d_in[22];
    const float* outb  = (const float*)d_in[23];

    // ---- workspace layout ----
    float* x = (float*)d_ws;                               // NTOK*256 fp32
    u16* qkvT = (u16*)(x + (size_t)NTOK*D_);               // [NL][768][256]
    u16* owT  = qkvT + (size_t)NL_*768*256;                // [NL][256][256]
    u16* w1T  = owT  + (size_t)NL_*65536;                  // [NL][1024][256]
    u16* w2T  = w1T  + (size_t)NL_*262144;                 // [NL][256][1024]
    float* tab = (float*)(w2T + (size_t)NL_*262144);       // L*32*2 fp32
    u16* bufs = (u16*)(tab + (size_t)L_*32*2);

    size_t fixedB = (size_t)((char*)bufs - (char*)d_ws);
    // layout: Xn[ch + PADR*256] | QKVc[3ch] | Ac[ch] | pad[PADR*1024] | kvf
    auto needed = [&](int nb) -> size_t {
        size_t ch = (size_t)nb * L_ * D_;
        return fixedB + (ch + (size_t)PADR*256)*2 + (4*ch + (size_t)PADR*1024)*2
               + (size_t)nb*NH_*4096*4;
    };
    int nbc = 32;
    while (nbc > 1 && needed(nbc) > ws_size) nbc >>= 1;
    const int nch = B_ / nbc;
    const int RCn = nbc * L_;
    const size_t CH = (size_t)nbc * L_ * D_;

    u16* Xn   = bufs;                          // CH (+ pad rows)
    u16* QKVc = Xn + CH + (size_t)PADR*256;    // 3*CH, row stride 768 (Q|K|V)
    u16* Ac   = QKVc + 3*CH;                   // CH (+ shared pad after)
    u16* Hc   = QKVc;                          // alias: MLP hidden = 4*CH (+ pad)
    float* kvf = (float*)(Ac + CH + (size_t)PADR*1024);    // nbc*4*4096 fp32

    // ---- setup ----
    wcvt_kernel<<<(NL_*65536 + 255)/256, 256, 0, stream>>>(qw,  qkvT, 256, 256, 768*256, 0);
    wcvt_kernel<<<(NL_*65536 + 255)/256, 256, 0, stream>>>(kw,  qkvT, 256, 256, 768*256, 256);
    wcvt_kernel<<<(NL_*65536 + 255)/256, 256, 0, stream>>>(vw,  qkvT, 256, 256, 768*256, 512);
    wcvt_kernel<<<(NL_*65536 + 255)/256, 256, 0, stream>>>(oww, owT, 256, 256, 65536, 0);
    wcvt_kernel<<<(NL_*262144 + 255)/256, 256, 0, stream>>>(w1, w1T, 1024, 256, 262144, 0);
    wcvt_kernel<<<(NL_*262144 + 255)/256, 256, 0, stream>>>(w2, w2T, 256, 1024, 262144, 0);
    rope_table_kernel<<<(L_*32 + 255)/256, 256, 0, stream>>>(tab);
    proj_kernel<<<NTOK, 256, 0, stream>>>(obs, pw, pb, cls, x);

    const int gy  = (RCn + 127)/128;
    const int lnb = (RCn + 3)/4;
    const int nbh = nbc*NH_;

    for (int layer = 0; layer < NL_; ++layer) {
        const u16* qkvT_l = qkvT + (size_t)layer*768*256;
        const u16* owT_l  = owT  + (size_t)layer*65536;
        const u16* w1T_l  = w1T  + (size_t)layer*262144;
        const u16* w2T_l  = w2T  + (size_t)layer*262144;
        const float* b1_l = b1 + (size_t)layer*1024;
        const float* b2_l = b2 + (size_t)layer*D_;

        for (int c = 0; c < nch; ++c) {
            float* xc = x + (size_t)c*RCn*D_;
            ln_f2b_kernel<<<lnb, 256, 0, stream>>>(xc, n1g + layer*D_, n1b + layer*D_, Xn, RCn);
            gemm_bf16<0><<<dim3(6, gy), 256, 0, stream>>>(Xn, qkvT_l, nullptr, QKVc, nullptr, RCn, 768, 256, 768);
            lnrope_kernel<<<lnb, 256, 0, stream>>>(QKVc,       gq + layer*D_, bq + layer*D_, tab, RCn, 768);
            lnrope_kernel<<<lnb, 256, 0, stream>>>(QKVc + 256, gk + layer*D_, bk + layer*D_, tab, RCn, 768);
            zero_kernel<<<(nbh*4096 + 255)/256, 256, 0, stream>>>(kvf, nbh*4096);
            kv_kernel<<<dim3(nbh, KV_NCHK), 256, 0, stream>>>(QKVc + 256, QKVc + 512, kvf, 768);
            attn_kernel<<<dim3(ATT_NTL, nbh), 256, 0, stream>>>(QKVc, kvf, Ac, 768);
            gemm_bf16<2><<<dim3(2, gy), 256, 0, stream>>>(Ac, owT_l, nullptr, nullptr, xc, RCn, 256, 256, 256);
            // MLP (hidden aliases QKVc..Ac+pad, all dead by now)
            ln_f2b_kernel<<<lnb, 256, 0, stream>>>(xc, n2g + layer*D_, n2b + layer*D_, Xn, RCn);
            gemm_bf16<1><<<dim3(8, gy), 256, 0, stream>>>(Xn, w1T_l, b1_l, Hc, nullptr, RCn, 1024, 256, 1024);
            gemm_bf16<3><<<dim3(2, gy), 256, 0, stream>>>(Hc, w2T_l, b2_l, nullptr, xc, RCn, 256, 1024, 256);
        }
    }

    head_kernel<<<B_, 256, 0, stream>>>(x, obs, fng, fnb, outw, outb, (float*)d_out);
}

// Round 6
// 2669.199 us; speedup vs baseline: 7.2162x; 1.1411x over previous
//
#include <hip/hip_runtime.h>
#include <math.h>

typedef unsigned short u16;
typedef __attribute__((ext_vector_type(8))) short short8;
typedef __attribute__((ext_vector_type(4))) short short4v;
typedef __attribute__((ext_vector_type(4))) float f32x4;

// ---------------- problem constants ----------------
constexpr int B_    = 32;
constexpr int HIST_ = 10, C_ = 11, H_ = 15, W_ = 20;
constexpr int D_    = 256, NH_ = 4, NL_ = 4, HD_ = 64;
constexpr int OUT_  = 256, ADIM_ = 20;
constexpr int L_    = HIST_*H_*W_ + 1;      // 3001
constexpr int VIS_  = HIST_*C_*H_*W_;       // 33000
constexpr int NTOK  = B_*L_;                // 96032
constexpr int OBSROW = VIS_ + ADIM_;        // 33020
constexpr int PADR  = 112;                  // extra rows so DMA reads stay in-bounds

// ---------------- bf16 helpers ----------------
__device__ __forceinline__ float bf2f(u16 u) {
    return __uint_as_float(((unsigned)u) << 16);
}
__device__ __forceinline__ u16 f2bf(float f) {
    unsigned u = __float_as_uint(f);
    u = u + 0x7FFFu + ((u >> 16) & 1u);
    return (u16)(u >> 16);
}
__device__ __forceinline__ f32x4 mfma16(short8 a, short8 b, f32x4 c) {
    return __builtin_amdgcn_mfma_f32_16x16x32_bf16(a, b, c, 0, 0, 0);
}
__device__ __forceinline__ void gload16(const u16* gsrc, u16* ldsdst) {
    __builtin_amdgcn_global_load_lds(
        (const __attribute__((address_space(1))) unsigned int*)gsrc,
        (__attribute__((address_space(3))) unsigned int*)ldsdst,
        16, 0, 0);
}

// ---------------- setup kernels ----------------
__global__ void zero_kernel(float* __restrict__ p, int n) {
    int i = blockIdx.x*256 + threadIdx.x;
    if (i < n) p[i] = 0.f;
}

// dst[l][dstOff+n][k] = bf16(src[l][k][n]); dst layer stride dstLS
__global__ void wcvt_kernel(const float* __restrict__ src, u16* __restrict__ dst,
                            int Nn, int Kk, int dstLS, int dstOff) {
    int idx = blockIdx.x*256 + threadIdx.x;
    int tot = NL_*Nn*Kk;
    if (idx >= tot) return;
    int l = idx / (Nn*Kk);
    int rem = idx % (Nn*Kk);
    int n = rem / Kk, k = rem % Kk;
    dst[(size_t)l*dstLS + (size_t)(dstOff+n)*Kk + k] = f2bf(src[(size_t)l*Kk*Nn + (size_t)k*Nn + n]);
}

__global__ void rope_table_kernel(float* __restrict__ tab) {
    int idx = blockIdx.x*256 + threadIdx.x;
    if (idx >= L_*32) return;
    int t = idx >> 5, i = idx & 31;
    float freq = powf(10000.f, -2.f*(float)i/(float)HD_);
    float ang = (float)t * freq;
    tab[idx*2]   = cosf(ang);
    tab[idx*2+1] = sinf(ang);
}

__global__ void proj_kernel(const float* __restrict__ obs, const float* __restrict__ pw,
                            const float* __restrict__ pb, const float* __restrict__ cls,
                            float* __restrict__ x) {
    __shared__ float vis[C_];
    int n = blockIdx.x;
    int b = n / L_, l = n % L_;
    int d = threadIdx.x;
    float out;
    if (l == 0) {
        out = cls[d];
    } else {
        int t = l - 1;
        int hist = t / (H_*W_);
        int rem  = t % (H_*W_);
        if (d < C_) vis[d] = obs[(size_t)b*OBSROW + hist*(C_*H_*W_) + d*(H_*W_) + rem];
        __syncthreads();
        float acc = pb[d];
        #pragma unroll
        for (int c = 0; c < C_; ++c) acc += vis[c] * pw[c*D_ + d];
        out = acc;
    }
    x[(size_t)n*D_ + d] = out;
}

// ---------------- LayerNorm fp32 -> bf16 ----------------
__global__ __launch_bounds__(256) void ln_f2b_kernel(const float* __restrict__ in,
        const float* __restrict__ g, const float* __restrict__ bt,
        u16* __restrict__ out, int ntok) {
    int wave = threadIdx.x >> 6, lane = threadIdx.x & 63;
    int n = blockIdx.x*4 + wave;
    if (n >= ntok) return;
    float4 v = ((const float4*)(in + (size_t)n*D_))[lane];
    float s  = v.x + v.y + v.z + v.w;
    float sq = v.x*v.x + v.y*v.y + v.z*v.z + v.w*v.w;
    #pragma unroll
    for (int off = 32; off; off >>= 1) { s += __shfl_xor(s, off); sq += __shfl_xor(sq, off); }
    float mean = s * (1.f/D_);
    float var  = sq * (1.f/D_) - mean*mean;
    float r = rsqrtf(var + 1e-5f);
    float4 gg = ((const float4*)g)[lane];
    float4 bb = ((const float4*)bt)[lane];
    short4v o;
    o.x = (short)f2bf((v.x-mean)*r*gg.x + bb.x);
    o.y = (short)f2bf((v.y-mean)*r*gg.y + bb.y);
    o.z = (short)f2bf((v.z-mean)*r*gg.z + bb.z);
    o.w = (short)f2bf((v.w-mean)*r*gg.w + bb.w);
    *(short4v*)(out + (size_t)n*D_ + lane*4) = o;
}

// ---------------- fused LN + RoPE + SiLU (bf16 in-place, row stride ld) ----------------
__global__ __launch_bounds__(256) void lnrope_kernel(u16* __restrict__ q,
        const float* __restrict__ g, const float* __restrict__ bt,
        const float* __restrict__ tab, int ntok, int ld) {
    int wave = threadIdx.x >> 6, lane = threadIdx.x & 63;
    int n = blockIdx.x*4 + wave;
    if (n >= ntok) return;
    int l = n % L_;
    short4v raw = *(const short4v*)(q + (size_t)n*ld + lane*4);
    float v0 = bf2f((u16)raw.x), v1 = bf2f((u16)raw.y), v2 = bf2f((u16)raw.z), v3 = bf2f((u16)raw.w);
    float s  = v0+v1+v2+v3;
    float sq = v0*v0+v1*v1+v2*v2+v3*v3;
    #pragma unroll
    for (int off = 32; off; off >>= 1) { s += __shfl_xor(s, off); sq += __shfl_xor(sq, off); }
    float mean = s * (1.f/D_);
    float var  = sq * (1.f/D_) - mean*mean;
    float r = rsqrtf(var + 1e-5f);
    float4 gg = ((const float4*)g)[lane];
    float4 bb = ((const float4*)bt)[lane];
    float o0 = (v0-mean)*r*gg.x + bb.x;
    float o1 = (v1-mean)*r*gg.y + bb.y;
    float o2 = (v2-mean)*r*gg.z + bb.z;
    float o3 = (v3-mean)*r*gg.w + bb.w;
    float p0 = __shfl_xor(o0, 8), p1 = __shfl_xor(o1, 8);
    float p2 = __shfl_xor(o2, 8), p3 = __shfl_xor(o3, 8);
    bool first = (lane & 15) < 8;
    const float4* tp = (const float4*)(tab + ((size_t)l*32 + (lane&7)*4)*2);
    float4 t01 = tp[0], t23 = tp[1];
    float r0 = first ? o0*t01.x - p0*t01.y : o0*t01.x + p0*t01.y;
    float r1 = first ? o1*t01.z - p1*t01.w : o1*t01.z + p1*t01.w;
    float r2 = first ? o2*t23.x - p2*t23.y : o2*t23.x + p2*t23.y;
    float r3 = first ? o3*t23.z - p3*t23.w : o3*t23.z + p3*t23.w;
    r0 = r0 / (1.f + expf(-r0));
    r1 = r1 / (1.f + expf(-r1));
    r2 = r2 / (1.f + expf(-r2));
    r3 = r3 / (1.f + expf(-r3));
    short4v o;
    o.x = (short)f2bf(r0); o.y = (short)f2bf(r1);
    o.z = (short)f2bf(r2); o.w = (short)f2bf(r3);
    *(short4v*)(q + (size_t)n*ld + lane*4) = o;
}

// ---------------- bf16 MFMA GEMM, global_load_lds staging ----------------
// C[M,N] = A[M,K] @ Wt[N,K]^T. 128x128 tile, BK=32, 4 waves (2x2), 16x16x32 MFMA.
// A row stride = lda (>= K). PB: per-batch mode — blockIdx.z selects batch:
// A += z*M*lda, Wt += z*N*K, output row base = z*M.
// EPI: 0 bf16 out; 1 +bias,GELU,bf16; 2 fp32 residual add; 3 +bias fp32 residual add
template<int EPI, bool PB>
__global__ __launch_bounds__(256) void gemm_bf16(const u16* __restrict__ A, int lda,
        const u16* __restrict__ Wt, const float* __restrict__ bias,
        u16* __restrict__ Cb, float* __restrict__ Xres, int M, int N, int K, int ldc) {
    __shared__ u16 As[128*32];
    __shared__ u16 Bs[128*32];
    // XCD-chunked block remap within the (x,y) plane
    const int gx = gridDim.x;
    int n = blockIdx.y * gx + blockIdx.x;
    const int nwg = gx * gridDim.y;
    if ((nwg & 7) == 0) n = (n & 7) * (nwg >> 3) + (n >> 3);
    const int bx = n % gx, by = n / gx;
    const int row0 = by*128, col0 = bx*128;

    size_t zrow = 0;
    if (PB) {
        int z = blockIdx.z;
        A  += (size_t)z * M * lda;
        Wt += (size_t)z * N * K;
        zrow = (size_t)z * M;
    }

    const int tid = threadIdx.x;
    const int wid = tid >> 6, lane = tid & 63;
    const int wr = wid >> 1, wc = wid & 1;

    f32x4 acc[4][4];
    #pragma unroll
    for (int i = 0; i < 4; ++i)
        #pragma unroll
        for (int j = 0; j < 4; ++j) {
            f32x4 z; z.x = 0.f; z.y = 0.f; z.z = 0.f; z.w = 0.f;
            acc[i][j] = z;
        }

    // DMA staging: lane l of instr i -> row r=(wid*2+i)*16+(l>>2), stored slot l&3.
    const int r0s = wid*32 + (lane>>2);
    const int r1s = r0s + 16;
    const int s0 = ((lane&3) - (r0s>>1)) & 3;
    const int s1 = ((lane&3) - (r1s>>1)) & 3;
    const u16* a0p = A  + (size_t)(row0 + r0s)*lda + s0*8;
    const u16* a1p = A  + (size_t)(row0 + r1s)*lda + s1*8;
    const u16* b0p = Wt + (size_t)(col0 + r0s)*K + s0*8;
    const u16* b1p = Wt + (size_t)(col0 + r1s)*K + s1*8;
    u16* lA0 = As + (wid*2+0)*512;
    u16* lA1 = As + (wid*2+1)*512;
    u16* lB0 = Bs + (wid*2+0)*512;
    u16* lB1 = Bs + (wid*2+1)*512;

    // fragment read offsets (swizzled): row*32 + ((kg + (row>>1))&3)*8
    const int kg = lane >> 4, li = lane & 15;
    int aoff[4], boff[4];
    #pragma unroll
    for (int mi = 0; mi < 4; ++mi) {
        int row = wr*64 + mi*16 + li;
        aoff[mi] = row*32 + ((kg + (row>>1)) & 3)*8;
    }
    #pragma unroll
    for (int ni = 0; ni < 4; ++ni) {
        int row = wc*64 + ni*16 + li;
        boff[ni] = row*32 + ((kg + (row>>1)) & 3)*8;
    }

    // prologue: stage k-tile 0
    gload16(a0p, lA0); gload16(a1p, lA1);
    gload16(b0p, lB0); gload16(b1p, lB1);

    const int nk = K >> 5;
    for (int ks = 0; ks < nk; ++ks) {
        __syncthreads();
        short8 af[4], bfr[4];
        #pragma unroll
        for (int mi = 0; mi < 4; ++mi) af[mi] = *(const short8*)(As + aoff[mi]);
        #pragma unroll
        for (int ni = 0; ni < 4; ++ni) bfr[ni] = *(const short8*)(Bs + boff[ni]);
        __syncthreads();
        if (ks + 1 < nk) {
            const int k0 = (ks + 1) << 5;
            gload16(a0p + k0, lA0); gload16(a1p + k0, lA1);
            gload16(b0p + k0, lB0); gload16(b1p + k0, lB1);
        }
        #pragma unroll
        for (int mi = 0; mi < 4; ++mi)
            #pragma unroll
            for (int ni = 0; ni < 4; ++ni)
                acc[mi][ni] = mfma16(af[mi], bfr[ni], acc[mi][ni]);
    }

    #pragma unroll
    for (int mi = 0; mi < 4; ++mi) {
        int rbase = row0 + wr*64 + mi*16 + kg*4;
        #pragma unroll
        for (int ni = 0; ni < 4; ++ni) {
            int col = col0 + wc*64 + ni*16 + li;
            #pragma unroll
            for (int r = 0; r < 4; ++r) {
                int row = rbase + r;
                if (row >= M) continue;
                float v = acc[mi][ni][r];
                if (EPI == 1) { v += bias[col]; v = 0.5f*v*(1.f + erff(v*0.70710678118654752f)); }
                if (EPI == 3) { v += bias[col]; }
                if (EPI == 0 || EPI == 1) Cb[(zrow + row)*ldc + col] = f2bf(v);
                else                      Xres[(zrow + row)*ldc + col] += v;
            }
        }
    }
}

// ---------------- kv = K^T V per (b,h) via MFMA ----------------
// kv[d][e] = sum_l K[l][d] * V[l][e].  L split 4 ways; LDS-transposed 32-l tiles;
// 4 waves each compute a 32x32 quadrant; fp32 atomic merge into kvf.
constexpr int KV_LSPLIT = 4;
constexpr int KV_PART   = 768;            // 24 tiles of 32; 4*768 >= L_
__global__ __launch_bounds__(256) void kv_mfma_kernel(const u16* __restrict__ Kt,
        const u16* __restrict__ Vt, float* __restrict__ kvf, int ld) {
    __shared__ u16 kT[64][34];            // [d][l'] transposed, pad 2
    __shared__ u16 vT[64][34];
    const int bh = blockIdx.x;
    const int b = bh >> 2, h = bh & 3;
    const int tid = threadIdx.x;
    const int wid = tid >> 6, lane = tid & 63;
    const int kg = lane >> 4, li = lane & 15;
    const int wm = (wid >> 1)*32, wn = (wid & 1)*32;
    // staging: thread reads 8 contiguous d at one l
    const int sl = tid >> 3;              // 0..31
    const int sd = (tid & 7) * 8;
    const u16* kbase = Kt + ((size_t)b*L_)*ld + h*HD_ + sd;
    const u16* vbase = Vt + ((size_t)b*L_)*ld + h*HD_ + sd;

    f32x4 acc[2][2];
    #pragma unroll
    for (int i = 0; i < 2; ++i)
        #pragma unroll
        for (int j = 0; j < 2; ++j) {
            f32x4 z; z.x=0.f; z.y=0.f; z.z=0.f; z.w=0.f; acc[i][j] = z;
        }

    const int l0p = blockIdx.y * KV_PART;
    for (int t = 0; t < KV_PART/32; ++t) {
        int gl = l0p + t*32 + sl;
        short8 kk = {0,0,0,0,0,0,0,0}, vv = {0,0,0,0,0,0,0,0};
        if (gl < L_) {
            kk = *(const short8*)(kbase + (size_t)gl*ld);
            vv = *(const short8*)(vbase + (size_t)gl*ld);
        }
        __syncthreads();                  // prior frag reads done
        #pragma unroll
        for (int j = 0; j < 8; ++j) {
            kT[sd+j][sl] = (u16)kk[j];
            vT[sd+j][sl] = (u16)vv[j];
        }
        __syncthreads();
        short8 a0, a1, b0, b1;
        {   // 4B-granular reads (rows are 68B, not 16B-aligned)
            uint* d0 = (uint*)&a0; const uint* p0 = (const uint*)&kT[wm + li][kg*8];
            uint* d1 = (uint*)&a1; const uint* p1 = (const uint*)&kT[wm + 16 + li][kg*8];
            uint* d2 = (uint*)&b0; const uint* p2 = (const uint*)&vT[wn + li][kg*8];
            uint* d3 = (uint*)&b1; const uint* p3 = (const uint*)&vT[wn + 16 + li][kg*8];
            #pragma unroll
            for (int j = 0; j < 4; ++j) { d0[j]=p0[j]; d1[j]=p1[j]; d2[j]=p2[j]; d3[j]=p3[j]; }
        }
        acc[0][0] = mfma16(a0, b0, acc[0][0]);
        acc[0][1] = mfma16(a0, b1, acc[0][1]);
        acc[1][0] = mfma16(a1, b0, acc[1][0]);
        acc[1][1] = mfma16(a1, b1, acc[1][1]);
    }
    float* base = kvf + (size_t)bh*4096;
    #pragma unroll
    for (int mi = 0; mi < 2; ++mi)
        #pragma unroll
        for (int ni = 0; ni < 2; ++ni)
            #pragma unroll
            for (int r = 0; r < 4; ++r)
                atomicAdd(base + (wm + mi*16 + kg*4 + r)*64 + wn + ni*16 + li,
                          acc[mi][ni][r]);
}

// ---------------- M2T[b][n][h*64+d] = bf16( (1/8) sum_e kv[b,h,d,e] * ow[h*64+e][n] ) ----------------
__global__ __launch_bounds__(256) void m2_kernel(const float* __restrict__ kvf,
        const float* __restrict__ ow, u16* __restrict__ m2t) {
    __shared__ float kvs[64][64];
    const int bh = blockIdx.x;
    const int b = bh >> 2, h = bh & 3;
    const int tid = threadIdx.x;          // n = tid
    #pragma unroll
    for (int p = 0; p < 16; ++p)
        ((float*)kvs)[p*256 + tid] = kvf[(size_t)bh*4096 + p*256 + tid];
    __syncthreads();
    float acc[64];
    #pragma unroll
    for (int d = 0; d < 64; ++d) acc[d] = 0.f;
    for (int e = 0; e < 64; ++e) {
        float w = ow[(size_t)(h*64 + e)*256 + tid];
        #pragma unroll
        for (int d = 0; d < 64; ++d) acc[d] += kvs[d][e] * w;
    }
    u16* dst = m2t + ((size_t)b*256 + tid)*256 + h*64;
    #pragma unroll
    for (int d = 0; d < 64; ++d) dst[d] = f2bf(acc[d]*0.125f);
}

// ---------------- head ----------------
__global__ void head_kernel(const float* __restrict__ x, const float* __restrict__ obs,
                            const float* __restrict__ fng, const float* __restrict__ fnb,
                            const float* __restrict__ ow, const float* __restrict__ ob,
                            float* __restrict__ out) {
    __shared__ float row[D_ + ADIM_];
    __shared__ float red[8];
    int b = blockIdx.x, tid = threadIdx.x;
    float v = x[((size_t)b*L_)*D_ + tid];
    float s = v, sq = v*v;
    #pragma unroll
    for (int off = 32; off; off >>= 1) { s += __shfl_xor(s, off); sq += __shfl_xor(sq, off); }
    int wave = tid >> 6, lane = tid & 63;
    if (lane == 0) { red[wave] = s; red[4+wave] = sq; }
    __syncthreads();
    s  = red[0]+red[1]+red[2]+red[3];
    sq = red[4]+red[5]+red[6]+red[7];
    float mean = s*(1.f/D_), var = sq*(1.f/D_) - mean*mean;
    float r = rsqrtf(var + 1e-5f);
    row[tid] = (v-mean)*r*fng[tid] + fnb[tid];
    if (tid < ADIM_) row[D_+tid] = obs[(size_t)b*OBSROW + VIS_ + tid];
    __syncthreads();
    float acc = ob[tid];
    for (int j = 0; j < D_+ADIM_; ++j) acc += row[j]*ow[j*OUT_ + tid];
    out[(size_t)b*OUT_ + tid] = acc;
}

// ---------------- launch ----------------
extern "C" void kernel_launch(void* const* d_in, const int* in_sizes, int n_in,
                              void* d_out, int out_size, void* d_ws, size_t ws_size,
                              hipStream_t stream) {
    const float* obs   = (const float*)d_in[0];
    const float* pw    = (const float*)d_in[1];
    const float* pb    = (const float*)d_in[2];
    const float* cls   = (const float*)d_in[3];
    const float* qw    = (const float*)d_in[4];
    const float* kw    = (const float*)d_in[5];
    const float* vw    = (const float*)d_in[6];
    const float* oww   = (const float*)d_in[7];
    const float* gq    = (const float*)d_in[8];
    const float* bq    = (const float*)d_in[9];
    const float* gk    = (const float*)d_in[10];
    const float* bk    = (const float*)d_in[11];
    const float* n1g   = (const float*)d_in[12];
    const float* n1b   = (const float*)d_in[13];
    const float* n2g   = (const float*)d_in[14];
    const float* n2b   = (const float*)d_in[15];
    const float* w1    = (const float*)d_in[16];
    const float* b1    = (const float*)d_in[17];
    const float* w2    = (const float*)d_in[18];
    const float* b2    = (const float*)d_in[19];
    const float* fng   = (const float*)d_in[20];
    const float* fnb   = (const float*)d_in[21];
    const float* outw  = (const float*)d_in[22];
    const float* outb  = (const float*)d_in[23];

    // ---- workspace layout ----
    float* x = (float*)d_ws;                               // NTOK*256 fp32
    u16* qkvT = (u16*)(x + (size_t)NTOK*D_);               // [NL][768][256]
    u16* w1T  = qkvT + (size_t)NL_*768*256;                // [NL][1024][256]
    u16* w2T  = w1T  + (size_t)NL_*262144;                 // [NL][256][1024]
    float* tab = (float*)(w2T + (size_t)NL_*262144);       // L*32*2 fp32
    u16* bufs = (u16*)(tab + (size_t)L_*32*2);

    size_t fixedB = (size_t)((char*)bufs - (char*)d_ws);
    // per-chunk: Xn[nb*L*256 + PADR*256] | QKVH region [nb*L*1024 + PADR*1024]
    //            | M2T [nb*256*256] | kvf [nb*4*4096] f32
    auto needed = [&](int nb) -> size_t {
        size_t t = (size_t)nb * L_;
        return fixedB + (t*256 + (size_t)PADR*256)*2 + (t*1024 + (size_t)PADR*1024)*2
               + (size_t)nb*65536*2 + (size_t)nb*NH_*4096*4;
    };
    int nbc = 32;
    while (nbc > 1 && needed(nbc) > ws_size) nbc >>= 1;
    const int nch = B_ / nbc;
    const int RCn = nbc * L_;

    u16* Xn   = bufs;                                           // nb*L*256 (+pad)
    u16* QKVc = Xn + (size_t)RCn*256 + (size_t)PADR*256;        // ld=768 view
    u16* Hc   = QKVc;                                           // ld=1024 view (same region)
    u16* M2T  = QKVc + (size_t)RCn*1024 + (size_t)PADR*1024;    // nb*256*256
    float* kvf = (float*)(M2T + (size_t)nbc*65536);             // nb*4*4096 f32

    // ---- setup ----
    wcvt_kernel<<<(NL_*65536 + 255)/256, 256, 0, stream>>>(qw,  qkvT, 256, 256, 768*256, 0);
    wcvt_kernel<<<(NL_*65536 + 255)/256, 256, 0, stream>>>(kw,  qkvT, 256, 256, 768*256, 256);
    wcvt_kernel<<<(NL_*65536 + 255)/256, 256, 0, stream>>>(vw,  qkvT, 256, 256, 768*256, 512);
    wcvt_kernel<<<(NL_*262144 + 255)/256, 256, 0, stream>>>(w1, w1T, 1024, 256, 262144, 0);
    wcvt_kernel<<<(NL_*262144 + 255)/256, 256, 0, stream>>>(w2, w2T, 256, 1024, 262144, 0);
    rope_table_kernel<<<(L_*32 + 255)/256, 256, 0, stream>>>(tab);
    proj_kernel<<<NTOK, 256, 0, stream>>>(obs, pw, pb, cls, x);

    const int gy  = (RCn + 127)/128;
    const int lnb = (RCn + 3)/4;
    const int nbh = nbc*NH_;

    for (int layer = 0; layer < NL_; ++layer) {
        const u16* qkvT_l = qkvT + (size_t)layer*768*256;
        const u16* w1T_l  = w1T  + (size_t)layer*262144;
        const u16* w2T_l  = w2T  + (size_t)layer*262144;
        const float* ow_l = oww + (size_t)layer*65536;
        const float* b1_l = b1 + (size_t)layer*1024;
        const float* b2_l = b2 + (size_t)layer*D_;

        for (int c = 0; c < nch; ++c) {
            float* xc = x + (size_t)c*RCn*D_;
            ln_f2b_kernel<<<lnb, 256, 0, stream>>>(xc, n1g + layer*D_, n1b + layer*D_, Xn, RCn);
            gemm_bf16<0,false><<<dim3(6, gy), 256, 0, stream>>>(Xn, 256, qkvT_l, nullptr, QKVc, nullptr, RCn, 768, 256, 768);
            lnrope_kernel<<<lnb, 256, 0, stream>>>(QKVc,       gq + layer*D_, bq + layer*D_, tab, RCn, 768);
            lnrope_kernel<<<lnb, 256, 0, stream>>>(QKVc + 256, gk + layer*D_, bk + layer*D_, tab, RCn, 768);
            zero_kernel<<<(nbh*4096 + 255)/256, 256, 0, stream>>>(kvf, nbh*4096);
            kv_mfma_kernel<<<dim3(nbh, KV_LSPLIT), 256, 0, stream>>>(QKVc + 256, QKVc + 512, kvf, 768);
            m2_kernel<<<nbh, 256, 0, stream>>>(kvf, ow_l, M2T);
            // fused attn + O-proj: x += Q @ M2T^T (per-batch weights)
            gemm_bf16<2,true><<<dim3(2, 24, nbc), 256, 0, stream>>>(QKVc, 768, M2T, nullptr, nullptr, xc, L_, 256, 256, 256);
            // MLP
            ln_f2b_kernel<<<lnb, 256, 0, stream>>>(xc, n2g + layer*D_, n2b + layer*D_, Xn, RCn);
            gemm_bf16<1,false><<<dim3(8, gy), 256, 0, stream>>>(Xn, 256, w1T_l, b1_l, Hc, nullptr, RCn, 1024, 256, 1024);
            gemm_bf16<3,false><<<dim3(2, gy), 256, 0, stream>>>(Hc, 1024, w2T_l, b2_l, nullptr, xc, RCn, 256, 1024, 256);
        }
    }

    head_kernel<<<B_, 256, 0, stream>>>(x, obs, fng, fnb, outw, outb, (float*)d_out);
}